// Round 5
// baseline (500.506 us; speedup 1.0000x reference)
//
#include <hip/hip_runtime.h>
#include <hip/hip_bf16.h>
#include <math.h>

#define S_LEN 2048
#define BATCH 2
#define DMODEL 1024
#define NH 16
#define NKV 4
#define HDIM 64
#define EPS 1e-5f
#define MROWS (S_LEN*BATCH)  // 4096
// attention scale folded into Q at rope time, including log2(e) so softmax uses exp2
#define QSCALE (0.03125f * 1.44269504088896f)

#define AS1 __attribute__((address_space(1)))
#define AS3 __attribute__((address_space(3)))

typedef __attribute__((ext_vector_type(8))) short bf8_t;
typedef __attribute__((ext_vector_type(4))) float f4_t;
typedef _Float16 __attribute__((ext_vector_type(8))) h8_t;
typedef _Float16 __attribute__((ext_vector_type(4))) h4_t;

#define MFMA16(a,b,c) __builtin_amdgcn_mfma_f32_16x16x16f16(a,b,c,0,0,0)

__device__ __forceinline__ float exp2_fast(float x){ return __builtin_exp2f(x); }

__device__ __forceinline__ unsigned short f2bf(float f){
  __hip_bfloat16 b = __float2bfloat16(f);
  return __builtin_bit_cast(unsigned short, b);
}
__device__ __forceinline__ float gelu_f(float x){
  return 0.5f * x * (1.0f + erff(x * 0.7071067811865475f));
}

// ---------------- RMSNorm -> bf16 out: one block per row ---------------------
__global__ __launch_bounds__(256) void rmsnorm_k(const float* __restrict__ x,
                                                 const float* __restrict__ w,
                                                 __hip_bfloat16* __restrict__ o){
  size_t row = blockIdx.x;
  const float4* xr = (const float4*)(x + row * DMODEL);
  float4 v = xr[threadIdx.x];
  float ss = v.x*v.x + v.y*v.y + v.z*v.z + v.w*v.w;
  #pragma unroll
  for (int off = 32; off; off >>= 1) ss += __shfl_down(ss, off);
  __shared__ float sm[5];
  if ((threadIdx.x & 63) == 0) sm[threadIdx.x >> 6] = ss;
  __syncthreads();
  if (threadIdx.x == 0) sm[4] = rsqrtf((sm[0]+sm[1]+sm[2]+sm[3]) * (1.0f/DMODEL) + EPS);
  __syncthreads();
  float r = sm[4];
  float4 wv = ((const float4*)w)[threadIdx.x];
  ushort4 ob;
  ob.x = f2bf(v.x*r*wv.x); ob.y = f2bf(v.y*r*wv.y);
  ob.z = f2bf(v.z*r*wv.z); ob.w = f2bf(v.w*r*wv.w);
  ((ushort4*)(o + row * DMODEL))[threadIdx.x] = ob;
}

// ------------- cast fp32 [K][N] -> bf16 transposed [N][dstStride] ------------
__global__ __launch_bounds__(256) void cast_t_k(const float* __restrict__ src,
                                                __hip_bfloat16* __restrict__ dst,
                                                int N, int dstStride){
  __shared__ float t[32][33];
  int n0 = blockIdx.x*32, k0 = blockIdx.y*32;
  int tx = threadIdx.x, ty = threadIdx.y;
  #pragma unroll
  for (int i = 0; i < 4; ++i)
    t[ty*4+i][tx] = src[(size_t)(k0+ty*4+i)*N + n0 + tx];
  __syncthreads();
  #pragma unroll
  for (int i = 0; i < 4; ++i)
    dst[(size_t)(n0+ty*4+i)*dstStride + k0 + tx] = __float2bfloat16(t[tx][ty*4+i]);
}

__global__ __launch_bounds__(256) void bias_cat_k(const float* __restrict__ bq,
                                                  const float* __restrict__ bk,
                                                  const float* __restrict__ bv,
                                                  float* __restrict__ bqkv){
  int t = blockIdx.x*256 + threadIdx.x;
  float v = (t < 1024) ? bq[t] : (t < 1280 ? bk[t-1024] : bv[t-1280]);
  bqkv[t] = v;
}

// ---------------- bf16 MFMA GEMM v2 ------------------------------------------
// C[M,N] = A[M,K] @ Wt[N,K]^T. 128x128 tile, BK=32, 4 waves (2x2), 4x4 16x16.
// LDS layout per stage buffer: 8 rowgroups x [kc(4)][r16(16)][8el] -> fragment
// reads are 16-lane-contiguous 256B bursts (bank-conflict-free), staging dest
// is base + lane*16 (global_load_lds compatible). Double-buffered (2x16KB).
// EPI: 0 = +bias->fp32(P0) ; 1 = +bias,gelu->bf16(Cb) ; 2 = +bias,+res->fp32(P0)
//      3 = raw partial fp32 -> P[blockIdx.z]  (bias applied in reduce_k)
template<int EPI>
__global__ __launch_bounds__(256) void mgemm_k(const __hip_bfloat16* __restrict__ A,
                                               const __hip_bfloat16* __restrict__ Wt,
                                               const float* __restrict__ bias,
                                               const float* __restrict__ res,
                                               float* __restrict__ P0, float* __restrict__ P1,
                                               float* __restrict__ P2, float* __restrict__ P3,
                                               __hip_bfloat16* __restrict__ Cb,
                                               int N, int Kstride, int kLen){
  __shared__ __align__(16) __hip_bfloat16 As[2][4096];
  __shared__ __align__(16) __hip_bfloat16 Bs[2][4096];
  const int tid = threadIdx.x;
  const int w = tid >> 6, l = tid & 63;
  const int lr = l & 15, lc = l >> 4;         // row-in-16, k-chunk
  const int bm = blockIdx.y * 128, bn = blockIdx.x * 128;
  const int wm = (w >> 1) * 64, wn = (w & 1) * 64;
  const int kOff = blockIdx.z * kLen;

  // wave w stages rowgroups {2w, 2w+1} of both tiles
  const __hip_bfloat16* Ag0 = A  + (size_t)(bm + 2*w*16 + lr)*Kstride + kOff + lc*8;
  const __hip_bfloat16* Ag1 = Ag0 + 16*(size_t)Kstride;
  const __hip_bfloat16* Bg0 = Wt + (size_t)(bn + 2*w*16 + lr)*Kstride + kOff + lc*8;
  const __hip_bfloat16* Bg1 = Bg0 + 16*(size_t)Kstride;

  auto stage = [&](int buf, int k0){
    __builtin_amdgcn_global_load_lds((const AS1 void*)(Ag0 + k0), (AS3 void*)(&As[buf][(2*w+0)*512 + l*8]), 16, 0, 0);
    __builtin_amdgcn_global_load_lds((const AS1 void*)(Ag1 + k0), (AS3 void*)(&As[buf][(2*w+1)*512 + l*8]), 16, 0, 0);
    __builtin_amdgcn_global_load_lds((const AS1 void*)(Bg0 + k0), (AS3 void*)(&Bs[buf][(2*w+0)*512 + l*8]), 16, 0, 0);
    __builtin_amdgcn_global_load_lds((const AS1 void*)(Bg1 + k0), (AS3 void*)(&Bs[buf][(2*w+1)*512 + l*8]), 16, 0, 0);
  };

  f4_t acc[4][4] = {};
  const int nIter = kLen >> 5;
  stage(0, 0);
  for (int it = 0; it < nIter; ++it){
    const int cur = it & 1;
    __syncthreads();                 // drains stage(it); prev reads of cur^1 done
    if (it + 1 < nIter) stage(cur ^ 1, (it+1)*32);
    bf8_t af[4], bfr[4];
    #pragma unroll
    for (int mi = 0; mi < 4; ++mi)
      af[mi] = *(const bf8_t*)(&As[cur][((wm>>4)+mi)*512 + lc*128 + lr*8]);
    #pragma unroll
    for (int ni = 0; ni < 4; ++ni)
      bfr[ni] = *(const bf8_t*)(&Bs[cur][((wn>>4)+ni)*512 + lc*128 + lr*8]);
    #pragma unroll
    for (int mi = 0; mi < 4; ++mi)
      #pragma unroll
      for (int ni = 0; ni < 4; ++ni)
        acc[mi][ni] = __builtin_amdgcn_mfma_f32_16x16x32_bf16(af[mi], bfr[ni], acc[mi][ni], 0, 0, 0);
  }

  float* Cf = P0;
  if (EPI == 3)
    Cf = (blockIdx.z == 0) ? P0 : (blockIdx.z == 1) ? P1 : (blockIdx.z == 2) ? P2 : P3;

  // C/D layout: col = lane&15 (=lr), row = (lane>>4)*4 + r (=lc*4+r)
  #pragma unroll
  for (int ni = 0; ni < 4; ++ni){
    int col = bn + wn + ni*16 + lr;
    float bb = (EPI == 3) ? 0.0f : bias[col];
    #pragma unroll
    for (int mi = 0; mi < 4; ++mi){
      #pragma unroll
      for (int r = 0; r < 4; ++r){
        int row = bm + wm + mi*16 + lc*4 + r;
        size_t off = (size_t)row * N + col;
        float v = acc[mi][ni][r] + bb;
        if (EPI == 1)      Cb[off] = __float2bfloat16(gelu_f(v));
        else if (EPI == 2) Cf[off] = v + res[off];
        else               Cf[off] = v;
      }
    }
  }
}

// ---------------- split-K reduce: out = sum(partials) + bias (+res) ----------
template<int NS, int EPI>  // EPI 0: +bias->fp32 ; 2: +bias+res->fp32
__global__ __launch_bounds__(256) void reduce_k(const float* __restrict__ p0, const float* __restrict__ p1,
                                                const float* __restrict__ p2, const float* __restrict__ p3,
                                                const float* __restrict__ bias, const float* __restrict__ res,
                                                float* __restrict__ out, int N){
  size_t i4 = (size_t)blockIdx.x*256 + threadIdx.x;
  int col = (int)((i4 % (size_t)(N >> 2)) << 2);
  float4 v = ((const float4*)p0)[i4];
  float4 t = ((const float4*)p1)[i4];
  v.x += t.x; v.y += t.y; v.z += t.z; v.w += t.w;
  if (NS > 2){
    t = ((const float4*)p2)[i4]; v.x += t.x; v.y += t.y; v.z += t.z; v.w += t.w;
    t = ((const float4*)p3)[i4]; v.x += t.x; v.y += t.y; v.z += t.z; v.w += t.w;
  }
  float4 bb = *(const float4*)(bias + col);
  v.x += bb.x; v.y += bb.y; v.z += bb.z; v.w += bb.w;
  if (EPI == 2){
    float4 r = ((const float4*)res)[i4];
    v.x += r.x; v.y += r.y; v.z += r.z; v.w += r.w;
  }
  ((float4*)out)[i4] = v;
}

// ---------------- per-head RMSNorm + RoPE -> f16, one wave per (s,b,head) ----
__global__ __launch_bounds__(64) void rope_k(const float* __restrict__ in, const float* __restrict__ w,
                                             _Float16* __restrict__ out, int nh, int col0, int stride,
                                             float oscale){
  const int s = blockIdx.x;
  const int b = blockIdx.y / nh, hh = blockIdx.y % nh;
  const int lane = threadIdx.x;
  float v = in[((size_t)s * BATCH + b) * stride + col0 + hh*64 + lane];
  float ss = v * v;
  #pragma unroll
  for (int m = 32; m; m >>= 1) ss += __shfl_xor(ss, m);
  float r = rsqrtf(ss * (1.0f/64.0f) + EPS);
  v = v * r * w[lane];
  int i = lane & 31;
  float invf = powf(10000.0f, -((float)(2*i)) * (1.0f/64.0f));
  float ang = (float)s * invf;
  float c, sn;
  sincosf(ang, &sn, &c);
  float partner = __shfl_xor(v, 32);
  float rh = (lane < 32) ? -partner : partner;
  out[(((size_t)b * nh + hh) * S_LEN + s) * 64 + lane] = (_Float16)((v * c + rh * sn) * oscale);
}

// ---------------- V extract: qkvt fp32 [S,B,1536] -> Vt f16 [B*NKV][64][S] ---
__global__ __launch_bounds__(256) void vcast_k(const float* __restrict__ qkvt,
                                               _Float16* __restrict__ Vt){
  __shared__ float t[64][65];
  const int s0 = blockIdx.x * 64;
  const int bkv = blockIdx.y;
  const int b = bkv >> 2, kv = bkv & 3;
  const int tid = threadIdx.x;
  #pragma unroll
  for (int i = 0; i < 16; ++i){
    int idx = tid + 256*i;
    int sl = idx >> 6, d = idx & 63;
    t[d][sl] = qkvt[((size_t)(s0+sl)*BATCH + b)*1536 + 1280 + kv*64 + d];
  }
  __syncthreads();
  #pragma unroll
  for (int i = 0; i < 16; ++i){
    int idx = tid + 256*i;
    int d = idx >> 6, sl = idx & 63;
    Vt[((size_t)bkv*64 + d)*S_LEN + s0 + sl] = (_Float16)t[d][sl];
  }
}

// ---------------- MFMA flash attention -------------------------------------
__global__ __launch_bounds__(256) void attn2_k(const _Float16* __restrict__ Q,
                                               const _Float16* __restrict__ K,
                                               const _Float16* __restrict__ Vt,
                                               __hip_bfloat16* __restrict__ AO){
  __shared__ __align__(16) _Float16 Ks[8*512];
  __shared__ __align__(16) _Float16 Vs[8*512];
  const int bh = blockIdx.x;
  const int qb = (gridDim.y - 1) - blockIdx.y;
  const int b = bh >> 4, h = bh & 15;
  const int kvh = h >> 2;
  const int tid = threadIdx.x;
  const int w = tid >> 6, l = tid & 63;
  const int lr = l & 15, quad = l >> 4;

  const _Float16* qp = Q + ((size_t)bh * S_LEN + qb*64 + w*16 + lr) * 64;
  h8_t qf0 = *(const h8_t*)(qp + quad*8);
  h8_t qf1 = *(const h8_t*)(qp + 32 + quad*8);

  const _Float16* kbase = K  + (size_t)(b*NKV + kvh) * S_LEN * 64;
  const _Float16* vbase = Vt + (size_t)(b*NKV + kvh) * 64 * S_LEN;

  f4_t Od[4] = {};
  float m_i = -3.0e38f, l_i = 0.0f;

  for (int kt = 0; kt <= qb; ++kt){
    __syncthreads();
    #pragma unroll
    for (int ii = 0; ii < 4; ++ii){
      int i = w*4 + ii;
      if (i < 8){
        int cc = i >> 1, dh = i & 1;
        const _Float16* src = kbase + (size_t)(kt*64 + cc*16 + lr)*64 + dh*32 + quad*8;
        __builtin_amdgcn_global_load_lds((const AS1 void*)src, (AS3 void*)(Ks + i*512), 16, 0, 0);
      } else {
        int j = i - 8;
        int dd = j >> 1, cc32 = j & 1;
        const _Float16* src = vbase + (size_t)(dd*16 + lr)*S_LEN + kt*64 + cc32*32 + quad*8;
        __builtin_amdgcn_global_load_lds((const AS1 void*)src, (AS3 void*)(Vs + j*512), 16, 0, 0);
      }
    }
    __syncthreads();

    const bool diag = (kt == qb);
    f4_t sc[4];
    #pragma unroll
    for (int nc2 = 0; nc2 < 4; ++nc2){
      if (diag && nc2 > w){
        sc[nc2][0] = -1.0e30f; sc[nc2][1] = -1.0e30f;
        sc[nc2][2] = -1.0e30f; sc[nc2][3] = -1.0e30f;
        continue;
      }
      f4_t a = {};
      h8_t k0 = *(const h8_t*)(Ks + (nc2*2+0)*512 + l*8);
      h8_t k1 = *(const h8_t*)(Ks + (nc2*2+1)*512 + l*8);
      a = __builtin_amdgcn_mfma_f32_16x16x32_f16(k0, qf0, a, 0, 0, 0);
      a = __builtin_amdgcn_mfma_f32_16x16x32_f16(k1, qf1, a, 0, 0, 0);
      if (diag && nc2 == w){
        #pragma unroll
        for (int r = 0; r < 4; ++r)
          if (quad*4 + r > lr) a[r] = -1.0e30f;
      }
      sc[nc2] = a;
    }

    float mx = sc[0][0];
    #pragma unroll
    for (int nc2 = 0; nc2 < 4; ++nc2)
      #pragma unroll
      for (int r = 0; r < 4; ++r) mx = fmaxf(mx, sc[nc2][r]);
    mx = fmaxf(mx, __shfl_xor(mx, 16));
    mx = fmaxf(mx, __shfl_xor(mx, 32));
    float nm = fmaxf(mx, m_i);
    float alpha = exp2_fast(m_i - nm);
    m_i = nm;
    float rs = 0.0f;
    h4_t pf[4];
    #pragma unroll
    for (int nc2 = 0; nc2 < 4; ++nc2)
      #pragma unroll
      for (int r = 0; r < 4; ++r){
        float e = exp2_fast(sc[nc2][r] - nm);
        rs += e;
        pf[nc2][r] = (_Float16)e;
      }
    rs += __shfl_xor(rs, 16);
    rs += __shfl_xor(rs, 32);
    l_i = l_i * alpha + rs;
    #pragma unroll
    for (int dd = 0; dd < 4; ++dd)
      #pragma unroll
      for (int r = 0; r < 4; ++r) Od[dd][r] *= alpha;

    #pragma unroll
    for (int dd = 0; dd < 4; ++dd)
      #pragma unroll
      for (int nc2 = 0; nc2 < 4; ++nc2){
        if (diag && nc2 > w) continue;
        h4_t vf = *(const h4_t*)(Vs + (dd*2 + (nc2>>1))*512
                                 + (((nc2&1)*2 + (quad>>1))*16 + lr)*8 + (quad&1)*4);
        Od[dd] = MFMA16(vf, pf[nc2], Od[dd]);
      }
  }

  float inv = 1.0f / l_i;
  #pragma unroll
  for (int dd = 0; dd < 4; ++dd){
    ushort4 w4;
    w4.x = f2bf(Od[dd][0]*inv); w4.y = f2bf(Od[dd][1]*inv);
    w4.z = f2bf(Od[dd][2]*inv); w4.w = f2bf(Od[dd][3]*inv);
    size_t sg = (size_t)qb*64 + w*16 + lr;
    *(ushort4*)(AO + (sg*BATCH + b)*DMODEL + h*64 + dd*16 + quad*4) = w4;
  }
}

extern "C" void kernel_launch(void* const* d_in, const int* in_sizes, int n_in,
                              void* d_out, int out_size, void* d_ws, size_t ws_size,
                              hipStream_t stream){
  const float* x   = (const float*)d_in[0];
  const float* n1w = (const float*)d_in[1];
  const float* wq  = (const float*)d_in[2];
  const float* bq  = (const float*)d_in[3];
  const float* wk  = (const float*)d_in[4];
  const float* bk  = (const float*)d_in[5];
  const float* wv  = (const float*)d_in[6];
  const float* bv  = (const float*)d_in[7];
  const float* qnw = (const float*)d_in[8];
  const float* knw = (const float*)d_in[9];
  const float* wo  = (const float*)d_in[10];
  const float* bo  = (const float*)d_in[11];
  const float* n2w = (const float*)d_in[12];
  const float* w1  = (const float*)d_in[13];
  const float* b1  = (const float*)d_in[14];
  const float* w2  = (const float*)d_in[15];
  const float* b2  = (const float*)d_in[16];
  float* out = (float*)d_out;

  char* p = (char*)d_ws;
  auto carve = [&](size_t bytes)->char*{ char* r = p; p += (bytes + 255) & ~(size_t)255; return r; };
  // NOTE: h_bf and ao_bf must stay adjacent (w2 partial p3 spans both, 16.78 MB)
  __hip_bfloat16* h_bf   = (__hip_bfloat16*)carve((size_t)MROWS*DMODEL*2);
  __hip_bfloat16* ao_bf  = (__hip_bfloat16*)carve((size_t)MROWS*DMODEL*2);
  __hip_bfloat16* mid_bf = (__hip_bfloat16*)carve((size_t)MROWS*4096*2);
  __hip_bfloat16* wqkv_t = (__hip_bfloat16*)carve((size_t)1536*1024*2);
  __hip_bfloat16* wo_t   = (__hip_bfloat16*)carve((size_t)1024*1024*2);
  __hip_bfloat16* w1_t   = (__hip_bfloat16*)carve((size_t)4096*1024*2);
  __hip_bfloat16* w2_t   = (__hip_bfloat16*)carve((size_t)1024*4096*2);
  float* bqkv = (float*)carve(1536*4);
  float* qkvt = (float*)carve((size_t)MROWS*1536*4);
  _Float16* q_f  = (_Float16*)carve((size_t)BATCH*NH *S_LEN*64*2);
  _Float16* k_f  = (_Float16*)carve((size_t)BATCH*NKV*S_LEN*64*2);
  _Float16* vt_f = (_Float16*)carve((size_t)BATCH*NKV*64*S_LEN*2);
  float* x1   = (float*)carve((size_t)MROWS*DMODEL*4);
  float* ps   = (float*)carve((size_t)2*MROWS*DMODEL*4);   // 33.6 MB split-K scratch

  cast_t_k<<<dim3(32, 32), dim3(32,8), 0, stream>>>(wq, wqkv_t,               1024, 1024);
  cast_t_k<<<dim3( 8, 32), dim3(32,8), 0, stream>>>(wk, wqkv_t + 1024*1024,    256, 1024);
  cast_t_k<<<dim3( 8, 32), dim3(32,8), 0, stream>>>(wv, wqkv_t + 1280*1024,    256, 1024);
  cast_t_k<<<dim3(32, 32), dim3(32,8), 0, stream>>>(wo, wo_t,                 1024, 1024);
  cast_t_k<<<dim3(128,32), dim3(32,8), 0, stream>>>(w1, w1_t,                 4096, 1024);
  cast_t_k<<<dim3(32,128), dim3(32,8), 0, stream>>>(w2, w2_t,                 1024, 4096);
  bias_cat_k<<<6, 256, 0, stream>>>(bq, bk, bv, bqkv);

  rmsnorm_k<<<MROWS, 256, 0, stream>>>(x, n1w, h_bf);

  // QKV: M=4096 N=1536 K=1024, split-K=2 (p1 aliases dead mid_bf region)
  float* qkv_p1 = (float*)mid_bf;
  mgemm_k<3><<<dim3(12, 32, 2), 256, 0, stream>>>(h_bf, wqkv_t, nullptr, nullptr,
                                                  ps, qkv_p1, nullptr, nullptr, nullptr, 1536, 1024, 512);
  reduce_k<2,0><<<6144, 256, 0, stream>>>(ps, qkv_p1, nullptr, nullptr, bqkv, nullptr, qkvt, 1536);

  rope_k<<<dim3(S_LEN, BATCH*NH),  64, 0, stream>>>(qkvt, qnw, q_f, NH,  0,    1536, QSCALE);
  rope_k<<<dim3(S_LEN, BATCH*NKV), 64, 0, stream>>>(qkvt, knw, k_f, NKV, 1024, 1536, 1.0f);
  vcast_k<<<dim3(S_LEN/64, BATCH*NKV), 256, 0, stream>>>(qkvt, vt_f);
  attn2_k<<<dim3(BATCH*NH, S_LEN/64), 256, 0, stream>>>(q_f, k_f, vt_f, ao_bf);

  // O-proj: M=4096 N=1024 K=1024, split-K=2
  mgemm_k<3><<<dim3(8, 32, 2), 256, 0, stream>>>(ao_bf, wo_t, nullptr, nullptr,
                                                 ps, ps + (size_t)MROWS*DMODEL, nullptr, nullptr, nullptr, 1024, 1024, 512);
  reduce_k<2,2><<<4096, 256, 0, stream>>>(ps, ps + (size_t)MROWS*DMODEL, nullptr, nullptr, bo, x, x1, 1024);

  rmsnorm_k<<<MROWS, 256, 0, stream>>>(x1, n2w, h_bf);

  // MLP up: M=4096 N=4096 K=1024, unsplit (1024 blocks), fused gelu->bf16
  mgemm_k<1><<<dim3(32, 32, 1), 256, 0, stream>>>(h_bf, w1_t, b1, nullptr,
                                                  nullptr, nullptr, nullptr, nullptr, mid_bf, 4096, 1024, 1024);

  // MLP down: M=4096 N=1024 K=4096, split-K=4 (p2 aliases dead qkvt, p3 spans dead h_bf+ao_bf)
  float* w2_p2 = qkvt;
  float* w2_p3 = (float*)h_bf;
  mgemm_k<3><<<dim3(8, 32, 4), 256, 0, stream>>>(mid_bf, w2_t, nullptr, nullptr,
                                                 ps, ps + (size_t)MROWS*DMODEL, w2_p2, w2_p3, nullptr, 1024, 4096, 1024);
  reduce_k<4,2><<<4096, 256, 0, stream>>>(ps, ps + (size_t)MROWS*DMODEL, w2_p2, w2_p3, b2, x1, out, 1024);
}

// Round 6
// 453.784 us; speedup vs baseline: 1.1030x; 1.1030x over previous
//
#include <hip/hip_runtime.h>
#include <hip/hip_bf16.h>
#include <math.h>

#define S_LEN 2048
#define BATCH 2
#define DMODEL 1024
#define NH 16
#define NKV 4
#define HDIM 64
#define EPS 1e-5f
#define MROWS (S_LEN*BATCH)  // 4096
// attention scale folded into Q at rope time, including log2(e) so softmax uses exp2
#define QSCALE (0.03125f * 1.44269504088896f)

#define AS1 __attribute__((address_space(1)))
#define AS3 __attribute__((address_space(3)))

typedef __attribute__((ext_vector_type(8))) short bf8_t;
typedef __attribute__((ext_vector_type(4))) float f4_t;
typedef _Float16 __attribute__((ext_vector_type(8))) h8_t;
typedef _Float16 __attribute__((ext_vector_type(4))) h4_t;

#define MFMA16(a,b,c) __builtin_amdgcn_mfma_f32_16x16x16f16(a,b,c,0,0,0)

__device__ __forceinline__ float exp2_fast(float x){ return __builtin_exp2f(x); }

__device__ __forceinline__ unsigned short f2bf(float f){
  __hip_bfloat16 b = __float2bfloat16(f);
  return __builtin_bit_cast(unsigned short, b);
}
__device__ __forceinline__ float gelu_f(float x){
  return 0.5f * x * (1.0f + erff(x * 0.7071067811865475f));
}

// ---------------- RMSNorm -> bf16 out: one block per row ---------------------
__global__ __launch_bounds__(256) void rmsnorm_k(const float* __restrict__ x,
                                                 const float* __restrict__ w,
                                                 __hip_bfloat16* __restrict__ o){
  size_t row = blockIdx.x;
  const float4* xr = (const float4*)(x + row * DMODEL);
  float4 v = xr[threadIdx.x];
  float ss = v.x*v.x + v.y*v.y + v.z*v.z + v.w*v.w;
  #pragma unroll
  for (int off = 32; off; off >>= 1) ss += __shfl_down(ss, off);
  __shared__ float sm[5];
  if ((threadIdx.x & 63) == 0) sm[threadIdx.x >> 6] = ss;
  __syncthreads();
  if (threadIdx.x == 0) sm[4] = rsqrtf((sm[0]+sm[1]+sm[2]+sm[3]) * (1.0f/DMODEL) + EPS);
  __syncthreads();
  float r = sm[4];
  float4 wv = ((const float4*)w)[threadIdx.x];
  ushort4 ob;
  ob.x = f2bf(v.x*r*wv.x); ob.y = f2bf(v.y*r*wv.y);
  ob.z = f2bf(v.z*r*wv.z); ob.w = f2bf(v.w*r*wv.w);
  ((ushort4*)(o + row * DMODEL))[threadIdx.x] = ob;
}

// ------------- all weight transposes fused: fp32 [K][N] -> bf16 [N][stride] --
__global__ __launch_bounds__(256) void cast_all_k(const float* __restrict__ wq, const float* __restrict__ wk,
                                                  const float* __restrict__ wv, const float* __restrict__ wo,
                                                  const float* __restrict__ w1, const float* __restrict__ w2,
                                                  __hip_bfloat16* __restrict__ wqkv_t, __hip_bfloat16* __restrict__ wo_t,
                                                  __hip_bfloat16* __restrict__ w1_t,   __hip_bfloat16* __restrict__ w2_t){
  __shared__ float t[32][33];
  int b = blockIdx.x;
  const float* src; __hip_bfloat16* dst; int N, stride, nx;
  if (b < 1024)      { src=wq; dst=wqkv_t;               N=1024; stride=1024; nx=32;  }
  else if (b < 1280) { b-=1024; src=wk; dst=wqkv_t+1024*1024; N=256; stride=1024; nx=8; }
  else if (b < 1536) { b-=1280; src=wv; dst=wqkv_t+1280*1024; N=256; stride=1024; nx=8; }
  else if (b < 2560) { b-=1536; src=wo; dst=wo_t;        N=1024; stride=1024; nx=32;  }
  else if (b < 6656) { b-=2560; src=w1; dst=w1_t;        N=4096; stride=1024; nx=128; }
  else               { b-=6656; src=w2; dst=w2_t;        N=1024; stride=4096; nx=32;  }
  int n0 = (b % nx)*32, k0 = (b / nx)*32;
  int tx = threadIdx.x & 31, ty = threadIdx.x >> 5;
  #pragma unroll
  for (int i = 0; i < 4; ++i)
    t[ty*4+i][tx] = src[(size_t)(k0+ty*4+i)*N + n0 + tx];
  __syncthreads();
  #pragma unroll
  for (int i = 0; i < 4; ++i)
    dst[(size_t)(n0+ty*4+i)*stride + k0 + tx] = __float2bfloat16(t[tx][ty*4+i]);
}

__global__ __launch_bounds__(256) void bias_cat_k(const float* __restrict__ bq,
                                                  const float* __restrict__ bk,
                                                  const float* __restrict__ bv,
                                                  float* __restrict__ bqkv){
  int t = blockIdx.x*256 + threadIdx.x;
  float v = (t < 1024) ? bq[t] : (t < 1280 ? bk[t-1024] : bv[t-1280]);
  bqkv[t] = v;
}

// ---------------- bf16 MFMA GEMM v3 ------------------------------------------
// C[M,N] = A[M,K] @ Wt[N,K]^T. 128x128 tile, BK=64, 4 waves (2x2), 4x4 16x16.
// m97 2-barrier loop, single 2x16KB LDS stage. Chunked LDS layout:
// [rowgroup(8)][kchunk(8)][row16(16)][8 bf16] -> all ds_reads are 16-lane
// contiguous 1KB bursts (bank-conflict-free), staging dest = base + lane*16.
// EPI: 0 = +bias->fp32(P0) ; 1 = +bias,gelu->bf16(Cb) ; 2 = +bias,+res->fp32(P0)
//      3 = raw partial fp32 -> P[blockIdx.z]
template<int EPI>
__global__ __launch_bounds__(256) void mgemm_k(const __hip_bfloat16* __restrict__ A,
                                               const __hip_bfloat16* __restrict__ Wt,
                                               const float* __restrict__ bias,
                                               const float* __restrict__ res,
                                               float* __restrict__ P0, float* __restrict__ P1,
                                               __hip_bfloat16* __restrict__ Cb,
                                               int N, int Kstride, int kLen){
  __shared__ __align__(16) __hip_bfloat16 As[8192];   // 128 x 64
  __shared__ __align__(16) __hip_bfloat16 Bs[8192];
  const int tid = threadIdx.x;
  const int w = tid >> 6, l = tid & 63;
  const int lr = l & 15, lc = l >> 4;
  const int bm = blockIdx.y * 128, bn = blockIdx.x * 128;
  const int wm = (w >> 1) * 64, wn = (w & 1) * 64;
  const int kOff = blockIdx.z * kLen;

  // wave w stages rowgroups {2w, 2w+1}; load j covers kchunks j*4 + lc
  const __hip_bfloat16* Ag = A  + (size_t)(bm + 2*w*16 + lr)*Kstride + kOff + lc*8;
  const __hip_bfloat16* Bg = Wt + (size_t)(bn + 2*w*16 + lr)*Kstride + kOff + lc*8;

  f4_t acc[4][4] = {};

  for (int k0 = 0; k0 < kLen; k0 += 64){
    __syncthreads();
    #pragma unroll
    for (int rg = 0; rg < 2; ++rg)
      #pragma unroll
      for (int j = 0; j < 2; ++j){
        __builtin_amdgcn_global_load_lds((const AS1 void*)(Ag + rg*16*(size_t)Kstride + k0 + j*32),
                                         (AS3 void*)(&As[(2*w+rg)*1024 + j*512 + l*8]), 16, 0, 0);
        __builtin_amdgcn_global_load_lds((const AS1 void*)(Bg + rg*16*(size_t)Kstride + k0 + j*32),
                                         (AS3 void*)(&Bs[(2*w+rg)*1024 + j*512 + l*8]), 16, 0, 0);
      }
    __syncthreads();
    #pragma unroll
    for (int s = 0; s < 2; ++s){
      bf8_t af[4], bfr[4];
      #pragma unroll
      for (int mi = 0; mi < 4; ++mi)
        af[mi] = *(const bf8_t*)(&As[((wm>>4)+mi)*1024 + s*512 + l*8]);
      #pragma unroll
      for (int ni = 0; ni < 4; ++ni)
        bfr[ni] = *(const bf8_t*)(&Bs[((wn>>4)+ni)*1024 + s*512 + l*8]);
      #pragma unroll
      for (int mi = 0; mi < 4; ++mi)
        #pragma unroll
        for (int ni = 0; ni < 4; ++ni)
          acc[mi][ni] = __builtin_amdgcn_mfma_f32_16x16x32_bf16(af[mi], bfr[ni], acc[mi][ni], 0, 0, 0);
    }
  }

  float* Cf = (EPI == 3 && blockIdx.z) ? P1 : P0;

  // C/D layout: col = lane&15 (=lr), row = (lane>>4)*4 + r (=lc*4+r)
  #pragma unroll
  for (int ni = 0; ni < 4; ++ni){
    int col = bn + wn + ni*16 + lr;
    float bb = (EPI == 3) ? 0.0f : bias[col];
    #pragma unroll
    for (int mi = 0; mi < 4; ++mi){
      #pragma unroll
      for (int r = 0; r < 4; ++r){
        int row = bm + wm + mi*16 + lc*4 + r;
        size_t off = (size_t)row * N + col;
        float v = acc[mi][ni][r] + bb;
        if (EPI == 1)      Cb[off] = __float2bfloat16(gelu_f(v));
        else if (EPI == 2) Cf[off] = v + res[off];
        else               Cf[off] = v;
      }
    }
  }
}

// ---------------- split-K reduce: out = p0 + p1 + bias (+res) ----------------
template<int EPI>  // 0: +bias->fp32 ; 2: +bias+res->fp32
__global__ __launch_bounds__(256) void reduce_k(const float* __restrict__ p0, const float* __restrict__ p1,
                                                const float* __restrict__ bias, const float* __restrict__ res,
                                                float* __restrict__ out, int N){
  size_t i4 = (size_t)blockIdx.x*256 + threadIdx.x;
  int col = (int)((i4 % (size_t)(N >> 2)) << 2);
  float4 v = ((const float4*)p0)[i4];
  float4 t = ((const float4*)p1)[i4];
  v.x += t.x; v.y += t.y; v.z += t.z; v.w += t.w;
  float4 bb = *(const float4*)(bias + col);
  v.x += bb.x; v.y += bb.y; v.z += bb.z; v.w += bb.w;
  if (EPI == 2){
    float4 r = ((const float4*)res)[i4];
    v.x += r.x; v.y += r.y; v.z += r.z; v.w += r.w;
  }
  ((float4*)out)[i4] = v;
}

// -------- per-head RMSNorm + RoPE -> f16, Q and K in one launch --------------
__global__ __launch_bounds__(64) void rope2_k(const float* __restrict__ in,
                                              const float* __restrict__ qw, const float* __restrict__ kw,
                                              _Float16* __restrict__ qo, _Float16* __restrict__ ko){
  const int s = blockIdx.x;
  const int y = blockIdx.y;                  // b*20 + r ; r<16 -> Q head r, else K head r-16
  const int b = y / 20, r0 = y % 20;
  const bool isQ = (r0 < 16);
  const int hh = isQ ? r0 : (r0 - 16);
  const int col0 = isQ ? hh*64 : 1024 + hh*64;
  const int lane = threadIdx.x;
  float v = in[((size_t)s * BATCH + b) * 1536 + col0 + lane];
  float ss = v * v;
  #pragma unroll
  for (int m = 32; m; m >>= 1) ss += __shfl_xor(ss, m);
  float rr = rsqrtf(ss * (1.0f/64.0f) + EPS);
  v = v * rr * (isQ ? qw[lane] : kw[lane]);
  int i = lane & 31;
  float invf = powf(10000.0f, -((float)(2*i)) * (1.0f/64.0f));
  float ang = (float)s * invf;
  float c, sn;
  sincosf(ang, &sn, &c);
  float partner = __shfl_xor(v, 32);
  float rh = (lane < 32) ? -partner : partner;
  float o = (v * c + rh * sn) * (isQ ? QSCALE : 1.0f);
  _Float16* out = isQ ? (qo + (((size_t)b * NH  + hh) * S_LEN + s) * 64 + lane)
                      : (ko + (((size_t)b * NKV + hh) * S_LEN + s) * 64 + lane);
  *out = (_Float16)o;
}

// ---------------- V extract: qkvt fp32 [S,B,1536] -> Vt f16 [B*NKV][64][S] ---
__global__ __launch_bounds__(256) void vcast_k(const float* __restrict__ qkvt,
                                               _Float16* __restrict__ Vt){
  __shared__ float t[64][65];
  const int s0 = blockIdx.x * 64;
  const int bkv = blockIdx.y;
  const int b = bkv >> 2, kv = bkv & 3;
  const int tid = threadIdx.x;
  #pragma unroll
  for (int i = 0; i < 16; ++i){
    int idx = tid + 256*i;
    int sl = idx >> 6, d = idx & 63;
    t[d][sl] = qkvt[((size_t)(s0+sl)*BATCH + b)*1536 + 1280 + kv*64 + d];
  }
  __syncthreads();
  #pragma unroll
  for (int i = 0; i < 16; ++i){
    int idx = tid + 256*i;
    int d = idx >> 6, sl = idx & 63;
    Vt[((size_t)bkv*64 + d)*S_LEN + s0 + sl] = (_Float16)t[d][sl];
  }
}

// ---------------- MFMA flash attention -------------------------------------
__global__ __launch_bounds__(256) void attn2_k(const _Float16* __restrict__ Q,
                                               const _Float16* __restrict__ K,
                                               const _Float16* __restrict__ Vt,
                                               __hip_bfloat16* __restrict__ AO){
  __shared__ __align__(16) _Float16 Ks[8*512];
  __shared__ __align__(16) _Float16 Vs[8*512];
  const int bh = blockIdx.x;
  const int qb = (gridDim.y - 1) - blockIdx.y;
  const int b = bh >> 4, h = bh & 15;
  const int kvh = h >> 2;
  const int tid = threadIdx.x;
  const int w = tid >> 6, l = tid & 63;
  const int lr = l & 15, quad = l >> 4;

  const _Float16* qp = Q + ((size_t)bh * S_LEN + qb*64 + w*16 + lr) * 64;
  h8_t qf0 = *(const h8_t*)(qp + quad*8);
  h8_t qf1 = *(const h8_t*)(qp + 32 + quad*8);

  const _Float16* kbase = K  + (size_t)(b*NKV + kvh) * S_LEN * 64;
  const _Float16* vbase = Vt + (size_t)(b*NKV + kvh) * 64 * S_LEN;

  f4_t Od[4] = {};
  float m_i = -3.0e38f, l_i = 0.0f;

  for (int kt = 0; kt <= qb; ++kt){
    __syncthreads();
    #pragma unroll
    for (int ii = 0; ii < 4; ++ii){
      int i = w*4 + ii;
      if (i < 8){
        int cc = i >> 1, dh = i & 1;
        const _Float16* src = kbase + (size_t)(kt*64 + cc*16 + lr)*64 + dh*32 + quad*8;
        __builtin_amdgcn_global_load_lds((const AS1 void*)src, (AS3 void*)(Ks + i*512), 16, 0, 0);
      } else {
        int j = i - 8;
        int dd = j >> 1, cc32 = j & 1;
        const _Float16* src = vbase + (size_t)(dd*16 + lr)*S_LEN + kt*64 + cc32*32 + quad*8;
        __builtin_amdgcn_global_load_lds((const AS1 void*)src, (AS3 void*)(Vs + j*512), 16, 0, 0);
      }
    }
    __syncthreads();

    const bool diag = (kt == qb);
    f4_t sc[4];
    #pragma unroll
    for (int nc2 = 0; nc2 < 4; ++nc2){
      if (diag && nc2 > w){
        sc[nc2][0] = -1.0e30f; sc[nc2][1] = -1.0e30f;
        sc[nc2][2] = -1.0e30f; sc[nc2][3] = -1.0e30f;
        continue;
      }
      f4_t a = {};
      h8_t k0 = *(const h8_t*)(Ks + (nc2*2+0)*512 + l*8);
      h8_t k1 = *(const h8_t*)(Ks + (nc2*2+1)*512 + l*8);
      a = __builtin_amdgcn_mfma_f32_16x16x32_f16(k0, qf0, a, 0, 0, 0);
      a = __builtin_amdgcn_mfma_f32_16x16x32_f16(k1, qf1, a, 0, 0, 0);
      if (diag && nc2 == w){
        #pragma unroll
        for (int r = 0; r < 4; ++r)
          if (quad*4 + r > lr) a[r] = -1.0e30f;
      }
      sc[nc2] = a;
    }

    float mx = sc[0][0];
    #pragma unroll
    for (int nc2 = 0; nc2 < 4; ++nc2)
      #pragma unroll
      for (int r = 0; r < 4; ++r) mx = fmaxf(mx, sc[nc2][r]);
    mx = fmaxf(mx, __shfl_xor(mx, 16));
    mx = fmaxf(mx, __shfl_xor(mx, 32));
    float nm = fmaxf(mx, m_i);
    float alpha = exp2_fast(m_i - nm);
    m_i = nm;
    float rs = 0.0f;
    h4_t pf[4];
    #pragma unroll
    for (int nc2 = 0; nc2 < 4; ++nc2)
      #pragma unroll
      for (int r = 0; r < 4; ++r){
        float e = exp2_fast(sc[nc2][r] - nm);
        rs += e;
        pf[nc2][r] = (_Float16)e;
      }
    rs += __shfl_xor(rs, 16);
    rs += __shfl_xor(rs, 32);
    l_i = l_i * alpha + rs;
    #pragma unroll
    for (int dd = 0; dd < 4; ++dd)
      #pragma unroll
      for (int r = 0; r < 4; ++r) Od[dd][r] *= alpha;

    #pragma unroll
    for (int dd = 0; dd < 4; ++dd)
      #pragma unroll
      for (int nc2 = 0; nc2 < 4; ++nc2){
        if (diag && nc2 > w) continue;
        h4_t vf = *(const h4_t*)(Vs + (dd*2 + (nc2>>1))*512
                                 + (((nc2&1)*2 + (quad>>1))*16 + lr)*8 + (quad&1)*4);
        Od[dd] = MFMA16(vf, pf[nc2], Od[dd]);
      }
  }

  float inv = 1.0f / l_i;
  #pragma unroll
  for (int dd = 0; dd < 4; ++dd){
    ushort4 w4;
    w4.x = f2bf(Od[dd][0]*inv); w4.y = f2bf(Od[dd][1]*inv);
    w4.z = f2bf(Od[dd][2]*inv); w4.w = f2bf(Od[dd][3]*inv);
    size_t sg = (size_t)qb*64 + w*16 + lr;
    *(ushort4*)(AO + (sg*BATCH + b)*DMODEL + h*64 + dd*16 + quad*4) = w4;
  }
}

extern "C" void kernel_launch(void* const* d_in, const int* in_sizes, int n_in,
                              void* d_out, int out_size, void* d_ws, size_t ws_size,
                              hipStream_t stream){
  const float* x   = (const float*)d_in[0];
  const float* n1w = (const float*)d_in[1];
  const float* wq  = (const float*)d_in[2];
  const float* bq  = (const float*)d_in[3];
  const float* wk  = (const float*)d_in[4];
  const float* bk  = (const float*)d_in[5];
  const float* wv  = (const float*)d_in[6];
  const float* bv  = (const float*)d_in[7];
  const float* qnw = (const float*)d_in[8];
  const float* knw = (const float*)d_in[9];
  const float* wo  = (const float*)d_in[10];
  const float* bo  = (const float*)d_in[11];
  const float* n2w = (const float*)d_in[12];
  const float* w1  = (const float*)d_in[13];
  const float* b1  = (const float*)d_in[14];
  const float* w2  = (const float*)d_in[15];
  const float* b2  = (const float*)d_in[16];
  float* out = (float*)d_out;

  char* p = (char*)d_ws;
  auto carve = [&](size_t bytes)->char*{ char* r = p; p += (bytes + 255) & ~(size_t)255; return r; };
  __hip_bfloat16* h_bf   = (__hip_bfloat16*)carve((size_t)MROWS*DMODEL*2);
  __hip_bfloat16* ao_bf  = (__hip_bfloat16*)carve((size_t)MROWS*DMODEL*2);
  __hip_bfloat16* mid_bf = (__hip_bfloat16*)carve((size_t)MROWS*4096*2);
  __hip_bfloat16* wqkv_t = (__hip_bfloat16*)carve((size_t)1536*1024*2);
  __hip_bfloat16* wo_t   = (__hip_bfloat16*)carve((size_t)1024*1024*2);
  __hip_bfloat16* w1_t   = (__hip_bfloat16*)carve((size_t)4096*1024*2);
  __hip_bfloat16* w2_t   = (__hip_bfloat16*)carve((size_t)1024*4096*2);
  float* bqkv = (float*)carve(1536*4);
  float* qkvt = (float*)carve((size_t)MROWS*1536*4);
  _Float16* q_f  = (_Float16*)carve((size_t)BATCH*NH *S_LEN*64*2);
  _Float16* k_f  = (_Float16*)carve((size_t)BATCH*NKV*S_LEN*64*2);
  _Float16* vt_f = (_Float16*)carve((size_t)BATCH*NKV*64*S_LEN*2);
  float* x1   = (float*)carve((size_t)MROWS*DMODEL*4);
  float* ps   = (float*)carve((size_t)2*MROWS*DMODEL*4);   // split-K scratch (w2)

  cast_all_k<<<10752, 256, 0, stream>>>(wq, wk, wv, wo, w1, w2, wqkv_t, wo_t, w1_t, w2_t);
  bias_cat_k<<<6, 256, 0, stream>>>(bq, bk, bv, bqkv);

  rmsnorm_k<<<MROWS, 256, 0, stream>>>(x, n1w, h_bf);

  // QKV: M=4096 N=1536 K=1024
  mgemm_k<0><<<dim3(12, 32, 1), 256, 0, stream>>>(h_bf, wqkv_t, bqkv, nullptr,
                                                  qkvt, nullptr, nullptr, 1536, 1024, 1024);

  rope2_k<<<dim3(S_LEN, BATCH*20), 64, 0, stream>>>(qkvt, qnw, knw, q_f, k_f);
  vcast_k<<<dim3(S_LEN/64, BATCH*NKV), 256, 0, stream>>>(qkvt, vt_f);
  attn2_k<<<dim3(BATCH*NH, S_LEN/64), 256, 0, stream>>>(q_f, k_f, vt_f, ao_bf);

  // O-proj: M=4096 N=1024 K=1024, +residual
  mgemm_k<2><<<dim3(8, 32, 1), 256, 0, stream>>>(ao_bf, wo_t, bo, x,
                                                 x1, nullptr, nullptr, 1024, 1024, 1024);

  rmsnorm_k<<<MROWS, 256, 0, stream>>>(x1, n2w, h_bf);

  // MLP up: M=4096 N=4096 K=1024, fused gelu->bf16
  mgemm_k<1><<<dim3(32, 32, 1), 256, 0, stream>>>(h_bf, w1_t, b1, nullptr,
                                                  nullptr, nullptr, mid_bf, 4096, 1024, 1024);

  // MLP down: M=4096 N=1024 K=4096, split-K=2 + reduce(+bias+res)
  mgemm_k<3><<<dim3(8, 32, 2), 256, 0, stream>>>(mid_bf, w2_t, nullptr, nullptr,
                                                 ps, ps + (size_t)MROWS*DMODEL, nullptr, 1024, 4096, 2048);
  reduce_k<2><<<4096, 256, 0, stream>>>(ps, ps + (size_t)MROWS*DMODEL, b2, x1, out, 1024);
}

// Round 7
// 453.037 us; speedup vs baseline: 1.1048x; 1.0016x over previous
//
#include <hip/hip_runtime.h>
#include <hip/hip_bf16.h>
#include <math.h>

#define S_LEN 2048
#define BATCH 2
#define DMODEL 1024
#define NH 16
#define NKV 4
#define HDIM 64
#define EPS 1e-5f
#define MROWS (S_LEN*BATCH)  // 4096
// attention scale folded into Q at rope time, including log2(e) so softmax uses exp2
#define QSCALE (0.03125f * 1.44269504088896f)

#define AS1 __attribute__((address_space(1)))
#define AS3 __attribute__((address_space(3)))

typedef __attribute__((ext_vector_type(8))) short bf8_t;
typedef __attribute__((ext_vector_type(4))) float f4_t;
typedef _Float16 __attribute__((ext_vector_type(8))) h8_t;
typedef _Float16 __attribute__((ext_vector_type(4))) h4_t;

#define MFMA16(a,b,c) __builtin_amdgcn_mfma_f32_16x16x16f16(a,b,c,0,0,0)

__device__ __forceinline__ float exp2_fast(float x){ return __builtin_exp2f(x); }

__device__ __forceinline__ unsigned short f2bf(float f){
  __hip_bfloat16 b = __float2bfloat16(f);
  return __builtin_bit_cast(unsigned short, b);
}
__device__ __forceinline__ float bf2f(unsigned short u){
  return __builtin_bit_cast(float, (unsigned)u << 16);
}
__device__ __forceinline__ float gelu_f(float x){
  return 0.5f * x * (1.0f + erff(x * 0.7071067811865475f));
}

// ---------------- RMSNorm -> bf16 out: one block per row ---------------------
__global__ __launch_bounds__(256) void rmsnorm_k(const float* __restrict__ x,
                                                 const float* __restrict__ w,
                                                 __hip_bfloat16* __restrict__ o){
  size_t row = blockIdx.x;
  const float4* xr = (const float4*)(x + row * DMODEL);
  float4 v = xr[threadIdx.x];
  float ss = v.x*v.x + v.y*v.y + v.z*v.z + v.w*v.w;
  #pragma unroll
  for (int off = 32; off; off >>= 1) ss += __shfl_down(ss, off);
  __shared__ float sm[5];
  if ((threadIdx.x & 63) == 0) sm[threadIdx.x >> 6] = ss;
  __syncthreads();
  if (threadIdx.x == 0) sm[4] = rsqrtf((sm[0]+sm[1]+sm[2]+sm[3]) * (1.0f/DMODEL) + EPS);
  __syncthreads();
  float r = sm[4];
  float4 wv = ((const float4*)w)[threadIdx.x];
  ushort4 ob;
  ob.x = f2bf(v.x*r*wv.x); ob.y = f2bf(v.y*r*wv.y);
  ob.z = f2bf(v.z*r*wv.z); ob.w = f2bf(v.w*r*wv.w);
  ((ushort4*)(o + row * DMODEL))[threadIdx.x] = ob;
}

// ------------- all weight transposes fused: fp32 [K][N] -> bf16 [N][stride] --
__global__ __launch_bounds__(256) void cast_all_k(const float* __restrict__ wq, const float* __restrict__ wk,
                                                  const float* __restrict__ wv, const float* __restrict__ wo,
                                                  const float* __restrict__ w1, const float* __restrict__ w2,
                                                  __hip_bfloat16* __restrict__ wqkv_t, __hip_bfloat16* __restrict__ wo_t,
                                                  __hip_bfloat16* __restrict__ w1_t,   __hip_bfloat16* __restrict__ w2_t){
  __shared__ float t[32][33];
  int b = blockIdx.x;
  const float* src; __hip_bfloat16* dst; int N, stride, nx;
  if (b < 1024)      { src=wq; dst=wqkv_t;               N=1024; stride=1024; nx=32;  }
  else if (b < 1280) { b-=1024; src=wk; dst=wqkv_t+1024*1024; N=256; stride=1024; nx=8; }
  else if (b < 1536) { b-=1280; src=wv; dst=wqkv_t+1280*1024; N=256; stride=1024; nx=8; }
  else if (b < 2560) { b-=1536; src=wo; dst=wo_t;        N=1024; stride=1024; nx=32;  }
  else if (b < 6656) { b-=2560; src=w1; dst=w1_t;        N=4096; stride=1024; nx=128; }
  else               { b-=6656; src=w2; dst=w2_t;        N=1024; stride=4096; nx=32;  }
  int n0 = (b % nx)*32, k0 = (b / nx)*32;
  int tx = threadIdx.x & 31, ty = threadIdx.x >> 5;
  #pragma unroll
  for (int i = 0; i < 4; ++i)
    t[ty*4+i][tx] = src[(size_t)(k0+ty*4+i)*N + n0 + tx];
  __syncthreads();
  #pragma unroll
  for (int i = 0; i < 4; ++i)
    dst[(size_t)(n0+ty*4+i)*stride + k0 + tx] = __float2bfloat16(t[tx][ty*4+i]);
}

// ---------------- bf16 MFMA GEMM v4 ------------------------------------------
// C[M,N] = A[M,K] @ Wt[N,K]^T. 128x128 tile, BK=64, 4 waves (2x2), 4x4 16x16.
// m97 2-barrier loop; chunked conflict-free LDS layout (R6, verified 0 confl).
// EPI: 1 = +bias,gelu->bf16(Cb) ; 3 = raw bf16 partial -> Cb + z*MROWS*N
template<int EPI>
__global__ __launch_bounds__(256) void mgemm_k(const __hip_bfloat16* __restrict__ A,
                                               const __hip_bfloat16* __restrict__ Wt,
                                               const float* __restrict__ bias,
                                               __hip_bfloat16* __restrict__ Cb,
                                               int N, int Kstride, int kLen){
  __shared__ __align__(16) __hip_bfloat16 As[8192];   // 128 x 64
  __shared__ __align__(16) __hip_bfloat16 Bs[8192];
  const int tid = threadIdx.x;
  const int w = tid >> 6, l = tid & 63;
  const int lr = l & 15, lc = l >> 4;
  const int bm = blockIdx.y * 128, bn = blockIdx.x * 128;
  const int wm = (w >> 1) * 64, wn = (w & 1) * 64;
  const int kOff = blockIdx.z * kLen;

  const __hip_bfloat16* Ag = A  + (size_t)(bm + 2*w*16 + lr)*Kstride + kOff + lc*8;
  const __hip_bfloat16* Bg = Wt + (size_t)(bn + 2*w*16 + lr)*Kstride + kOff + lc*8;

  f4_t acc[4][4] = {};

  for (int k0 = 0; k0 < kLen; k0 += 64){
    __syncthreads();
    #pragma unroll
    for (int rg = 0; rg < 2; ++rg)
      #pragma unroll
      for (int j = 0; j < 2; ++j){
        __builtin_amdgcn_global_load_lds((const AS1 void*)(Ag + rg*16*(size_t)Kstride + k0 + j*32),
                                         (AS3 void*)(&As[(2*w+rg)*1024 + j*512 + l*8]), 16, 0, 0);
        __builtin_amdgcn_global_load_lds((const AS1 void*)(Bg + rg*16*(size_t)Kstride + k0 + j*32),
                                         (AS3 void*)(&Bs[(2*w+rg)*1024 + j*512 + l*8]), 16, 0, 0);
      }
    __syncthreads();
    #pragma unroll
    for (int s = 0; s < 2; ++s){
      bf8_t af[4], bfr[4];
      #pragma unroll
      for (int mi = 0; mi < 4; ++mi)
        af[mi] = *(const bf8_t*)(&As[((wm>>4)+mi)*1024 + s*512 + l*8]);
      #pragma unroll
      for (int ni = 0; ni < 4; ++ni)
        bfr[ni] = *(const bf8_t*)(&Bs[((wn>>4)+ni)*1024 + s*512 + l*8]);
      #pragma unroll
      for (int mi = 0; mi < 4; ++mi)
        #pragma unroll
        for (int ni = 0; ni < 4; ++ni)
          acc[mi][ni] = __builtin_amdgcn_mfma_f32_16x16x32_bf16(af[mi], bfr[ni], acc[mi][ni], 0, 0, 0);
    }
  }

  __hip_bfloat16* Cp = (EPI == 3) ? (Cb + (size_t)blockIdx.z * ((size_t)MROWS * N)) : Cb;

  // C/D layout: col = lane&15 (=lr), row = (lane>>4)*4 + r (=lc*4+r)
  #pragma unroll
  for (int ni = 0; ni < 4; ++ni){
    int col = bn + wn + ni*16 + lr;
    float bb = (EPI == 3) ? 0.0f : bias[col];
    #pragma unroll
    for (int mi = 0; mi < 4; ++mi){
      #pragma unroll
      for (int r = 0; r < 4; ++r){
        int row = bm + wm + mi*16 + lc*4 + r;
        size_t off = (size_t)row * N + col;
        float v = acc[mi][ni][r] + bb;
        if (EPI == 1) Cp[off] = __float2bfloat16(gelu_f(v));
        else          Cp[off] = __float2bfloat16(v);
      }
    }
  }
}

// -------- split-K reduce: out = sum_bf16(partials) + bias + res (fp32) -------
template<int NS>
__global__ __launch_bounds__(256) void reduce_k(const unsigned short* __restrict__ P,
                                                const float* __restrict__ bias,
                                                const float* __restrict__ res,
                                                float* __restrict__ out, int N){
  size_t i = ((size_t)blockIdx.x*256 + threadIdx.x) * 4;
  int col = (int)(i % (size_t)N);
  size_t stride = (size_t)MROWS * N;
  float a0=0,a1=0,a2=0,a3=0;
  #pragma unroll
  for (int p = 0; p < NS; ++p){
    ushort4 u = *(const ushort4*)(P + p*stride + i);
    a0 += bf2f(u.x); a1 += bf2f(u.y); a2 += bf2f(u.z); a3 += bf2f(u.w);
  }
  float4 bb = *(const float4*)(bias + col);
  float4 r4 = *(const float4*)(res + i);
  float4 o = make_float4(a0+bb.x+r4.x, a1+bb.y+r4.y, a2+bb.z+r4.z, a3+bb.w+r4.w);
  *(float4*)(out + i) = o;
}

// -------- per-head RMSNorm + RoPE -> f16, reads qkv partial pair + bias ------
__global__ __launch_bounds__(64) void rope2_k(const unsigned short* __restrict__ P,
                                              const float* __restrict__ bq, const float* __restrict__ bk,
                                              const float* __restrict__ qw, const float* __restrict__ kw,
                                              _Float16* __restrict__ qo, _Float16* __restrict__ ko){
  const int s = blockIdx.x;
  const int y = blockIdx.y;                  // b*20 + r ; r<16 -> Q head r, else K head r-16
  const int b = y / 20, r0 = y % 20;
  const bool isQ = (r0 < 16);
  const int hh = isQ ? r0 : (r0 - 16);
  const int col0 = isQ ? hh*64 : 1024 + hh*64;
  const int lane = threadIdx.x;
  const size_t pstride = (size_t)MROWS * 1536;
  size_t off = ((size_t)s * BATCH + b) * 1536 + col0 + lane;
  float v = bf2f(P[off]) + bf2f(P[off + pstride])
          + (isQ ? bq[hh*64 + lane] : bk[hh*64 + lane]);
  float ss = v * v;
  #pragma unroll
  for (int m = 32; m; m >>= 1) ss += __shfl_xor(ss, m);
  float rr = rsqrtf(ss * (1.0f/64.0f) + EPS);
  v = v * rr * (isQ ? qw[lane] : kw[lane]);
  int i = lane & 31;
  float invf = powf(10000.0f, -((float)(2*i)) * (1.0f/64.0f));
  float ang = (float)s * invf;
  float c, sn;
  sincosf(ang, &sn, &c);
  float partner = __shfl_xor(v, 32);
  float rh = (lane < 32) ? -partner : partner;
  float o = (v * c + rh * sn) * (isQ ? QSCALE : 1.0f);
  _Float16* outp = isQ ? (qo + (((size_t)b * NH  + hh) * S_LEN + s) * 64 + lane)
                       : (ko + (((size_t)b * NKV + hh) * S_LEN + s) * 64 + lane);
  *outp = (_Float16)o;
}

// -------- V extract from qkv partials -> Vt f16 [B*NKV][64][S] ---------------
__global__ __launch_bounds__(256) void vcast_k(const unsigned short* __restrict__ P,
                                               const float* __restrict__ bv,
                                               _Float16* __restrict__ Vt){
  __shared__ float t[64][65];
  const int s0 = blockIdx.x * 64;
  const int bkv = blockIdx.y;
  const int b = bkv >> 2, kv = bkv & 3;
  const int tid = threadIdx.x;
  const size_t pstride = (size_t)MROWS * 1536;
  #pragma unroll
  for (int i = 0; i < 16; ++i){
    int idx = tid + 256*i;
    int sl = idx >> 6, d = idx & 63;
    size_t off = ((size_t)(s0+sl)*BATCH + b)*1536 + 1280 + kv*64 + d;
    t[d][sl] = bf2f(P[off]) + bf2f(P[off + pstride]) + bv[kv*64 + d];
  }
  __syncthreads();
  #pragma unroll
  for (int i = 0; i < 16; ++i){
    int idx = tid + 256*i;
    int d = idx >> 6, sl = idx & 63;
    Vt[((size_t)bkv*64 + d)*S_LEN + s0 + sl] = (_Float16)t[d][sl];
  }
}

// ---------------- MFMA flash attention -------------------------------------
__global__ __launch_bounds__(256) void attn2_k(const _Float16* __restrict__ Q,
                                               const _Float16* __restrict__ K,
                                               const _Float16* __restrict__ Vt,
                                               __hip_bfloat16* __restrict__ AO){
  __shared__ __align__(16) _Float16 Ks[8*512];
  __shared__ __align__(16) _Float16 Vs[8*512];
  const int bh = blockIdx.x;
  const int qb = (gridDim.y - 1) - blockIdx.y;
  const int b = bh >> 4, h = bh & 15;
  const int kvh = h >> 2;
  const int tid = threadIdx.x;
  const int w = tid >> 6, l = tid & 63;
  const int lr = l & 15, quad = l >> 4;

  const _Float16* qp = Q + ((size_t)bh * S_LEN + qb*64 + w*16 + lr) * 64;
  h8_t qf0 = *(const h8_t*)(qp + quad*8);
  h8_t qf1 = *(const h8_t*)(qp + 32 + quad*8);

  const _Float16* kbase = K  + (size_t)(b*NKV + kvh) * S_LEN * 64;
  const _Float16* vbase = Vt + (size_t)(b*NKV + kvh) * 64 * S_LEN;

  f4_t Od[4] = {};
  float m_i = -3.0e38f, l_i = 0.0f;

  for (int kt = 0; kt <= qb; ++kt){
    __syncthreads();
    #pragma unroll
    for (int ii = 0; ii < 4; ++ii){
      int i = w*4 + ii;
      if (i < 8){
        int cc = i >> 1, dh = i & 1;
        const _Float16* src = kbase + (size_t)(kt*64 + cc*16 + lr)*64 + dh*32 + quad*8;
        __builtin_amdgcn_global_load_lds((const AS1 void*)src, (AS3 void*)(Ks + i*512), 16, 0, 0);
      } else {
        int j = i - 8;
        int dd = j >> 1, cc32 = j & 1;
        const _Float16* src = vbase + (size_t)(dd*16 + lr)*S_LEN + kt*64 + cc32*32 + quad*8;
        __builtin_amdgcn_global_load_lds((const AS1 void*)src, (AS3 void*)(Vs + j*512), 16, 0, 0);
      }
    }
    __syncthreads();

    const bool diag = (kt == qb);
    f4_t sc[4];
    #pragma unroll
    for (int nc2 = 0; nc2 < 4; ++nc2){
      if (diag && nc2 > w){
        sc[nc2][0] = -1.0e30f; sc[nc2][1] = -1.0e30f;
        sc[nc2][2] = -1.0e30f; sc[nc2][3] = -1.0e30f;
        continue;
      }
      f4_t a = {};
      h8_t k0 = *(const h8_t*)(Ks + (nc2*2+0)*512 + l*8);
      h8_t k1 = *(const h8_t*)(Ks + (nc2*2+1)*512 + l*8);
      a = __builtin_amdgcn_mfma_f32_16x16x32_f16(k0, qf0, a, 0, 0, 0);
      a = __builtin_amdgcn_mfma_f32_16x16x32_f16(k1, qf1, a, 0, 0, 0);
      if (diag && nc2 == w){
        #pragma unroll
        for (int r = 0; r < 4; ++r)
          if (quad*4 + r > lr) a[r] = -1.0e30f;
      }
      sc[nc2] = a;
    }

    float mx = sc[0][0];
    #pragma unroll
    for (int nc2 = 0; nc2 < 4; ++nc2)
      #pragma unroll
      for (int r = 0; r < 4; ++r) mx = fmaxf(mx, sc[nc2][r]);
    mx = fmaxf(mx, __shfl_xor(mx, 16));
    mx = fmaxf(mx, __shfl_xor(mx, 32));
    float nm = fmaxf(mx, m_i);
    float alpha = exp2_fast(m_i - nm);
    m_i = nm;
    float rs = 0.0f;
    h4_t pf[4];
    #pragma unroll
    for (int nc2 = 0; nc2 < 4; ++nc2)
      #pragma unroll
      for (int r = 0; r < 4; ++r){
        float e = exp2_fast(sc[nc2][r] - nm);
        rs += e;
        pf[nc2][r] = (_Float16)e;
      }
    rs += __shfl_xor(rs, 16);
    rs += __shfl_xor(rs, 32);
    l_i = l_i * alpha + rs;
    #pragma unroll
    for (int dd = 0; dd < 4; ++dd)
      #pragma unroll
      for (int r = 0; r < 4; ++r) Od[dd][r] *= alpha;

    #pragma unroll
    for (int dd = 0; dd < 4; ++dd)
      #pragma unroll
      for (int nc2 = 0; nc2 < 4; ++nc2){
        if (diag && nc2 > w) continue;
        h4_t vf = *(const h4_t*)(Vs + (dd*2 + (nc2>>1))*512
                                 + (((nc2&1)*2 + (quad>>1))*16 + lr)*8 + (quad&1)*4);
        Od[dd] = MFMA16(vf, pf[nc2], Od[dd]);
      }
  }

  float inv = 1.0f / l_i;
  #pragma unroll
  for (int dd = 0; dd < 4; ++dd){
    ushort4 w4;
    w4.x = f2bf(Od[dd][0]*inv); w4.y = f2bf(Od[dd][1]*inv);
    w4.z = f2bf(Od[dd][2]*inv); w4.w = f2bf(Od[dd][3]*inv);
    size_t sg = (size_t)qb*64 + w*16 + lr;
    *(ushort4*)(AO + (sg*BATCH + b)*DMODEL + h*64 + dd*16 + quad*4) = w4;
  }
}

extern "C" void kernel_launch(void* const* d_in, const int* in_sizes, int n_in,
                              void* d_out, int out_size, void* d_ws, size_t ws_size,
                              hipStream_t stream){
  const float* x   = (const float*)d_in[0];
  const float* n1w = (const float*)d_in[1];
  const float* wq  = (const float*)d_in[2];
  const float* bq  = (const float*)d_in[3];
  const float* wk  = (const float*)d_in[4];
  const float* bk  = (const float*)d_in[5];
  const float* wv  = (const float*)d_in[6];
  const float* bv  = (const float*)d_in[7];
  const float* qnw = (const float*)d_in[8];
  const float* knw = (const float*)d_in[9];
  const float* wo  = (const float*)d_in[10];
  const float* bo  = (const float*)d_in[11];
  const float* n2w = (const float*)d_in[12];
  const float* w1  = (const float*)d_in[13];
  const float* b1  = (const float*)d_in[14];
  const float* w2  = (const float*)d_in[15];
  const float* b2  = (const float*)d_in[16];
  float* out = (float*)d_out;

  char* p = (char*)d_ws;
  auto carve = [&](size_t bytes)->char*{ char* r = p; p += (bytes + 255) & ~(size_t)255; return r; };
  __hip_bfloat16* h_bf   = (__hip_bfloat16*)carve((size_t)MROWS*DMODEL*2);
  __hip_bfloat16* ao_bf  = (__hip_bfloat16*)carve((size_t)MROWS*DMODEL*2);
  __hip_bfloat16* mid_bf = (__hip_bfloat16*)carve((size_t)MROWS*4096*2);
  __hip_bfloat16* wqkv_t = (__hip_bfloat16*)carve((size_t)1536*1024*2);
  __hip_bfloat16* wo_t   = (__hip_bfloat16*)carve((size_t)1024*1024*2);
  __hip_bfloat16* w1_t   = (__hip_bfloat16*)carve((size_t)4096*1024*2);
  __hip_bfloat16* w2_t   = (__hip_bfloat16*)carve((size_t)1024*4096*2);
  __hip_bfloat16* qkv_p  = (__hip_bfloat16*)carve((size_t)2*MROWS*1536*2);  // qkv split-2 partials
  _Float16* q_f  = (_Float16*)carve((size_t)BATCH*NH *S_LEN*64*2);
  _Float16* k_f  = (_Float16*)carve((size_t)BATCH*NKV*S_LEN*64*2);
  _Float16* vt_f = (_Float16*)carve((size_t)BATCH*NKV*64*S_LEN*2);
  float* x1   = (float*)carve((size_t)MROWS*DMODEL*4);
  __hip_bfloat16* ps = (__hip_bfloat16*)carve((size_t)4*MROWS*DMODEL*2);    // wo(2)/w2(4) partials

  cast_all_k<<<10752, 256, 0, stream>>>(wq, wk, wv, wo, w1, w2, wqkv_t, wo_t, w1_t, w2_t);

  rmsnorm_k<<<MROWS, 256, 0, stream>>>(x, n1w, h_bf);

  // QKV: M=4096 N=1536 K=1024, split-K=2 (768 blocks = 3/CU), bf16 partials
  mgemm_k<3><<<dim3(12, 32, 2), 256, 0, stream>>>(h_bf, wqkv_t, nullptr, qkv_p, 1536, 1024, 512);

  rope2_k<<<dim3(S_LEN, BATCH*20), 64, 0, stream>>>((const unsigned short*)qkv_p, bq, bk, qnw, knw, q_f, k_f);
  vcast_k<<<dim3(S_LEN/64, BATCH*NKV), 256, 0, stream>>>((const unsigned short*)qkv_p, bv, vt_f);
  attn2_k<<<dim3(BATCH*NH, S_LEN/64), 256, 0, stream>>>(q_f, k_f, vt_f, ao_bf);

  // O-proj: M=4096 N=1024 K=1024, split-K=2 (512 blocks), reduce(+bias+res)
  mgemm_k<3><<<dim3(8, 32, 2), 256, 0, stream>>>(ao_bf, wo_t, nullptr, ps, 1024, 1024, 512);
  reduce_k<2><<<4096, 256, 0, stream>>>((const unsigned short*)ps, bo, x, x1, 1024);

  rmsnorm_k<<<MROWS, 256, 0, stream>>>(x1, n2w, h_bf);

  // MLP up: M=4096 N=4096 K=1024 (1024 blocks = 4/CU), fused gelu->bf16
  mgemm_k<1><<<dim3(32, 32, 1), 256, 0, stream>>>(h_bf, w1_t, b1, mid_bf, 4096, 1024, 1024);

  // MLP down: M=4096 N=1024 K=4096, split-K=4 (1024 blocks = 4/CU)
  mgemm_k<3><<<dim3(8, 32, 4), 256, 0, stream>>>(mid_bf, w2_t, nullptr, ps, 1024, 4096, 1024);
  reduce_k<4><<<4096, 256, 0, stream>>>((const unsigned short*)ps, b2, x1, out, 1024);
}

// Round 8
// 437.298 us; speedup vs baseline: 1.1445x; 1.0360x over previous
//
#include <hip/hip_runtime.h>
#include <hip/hip_bf16.h>
#include <math.h>

#define S_LEN 2048
#define BATCH 2
#define DMODEL 1024
#define NH 16
#define NKV 4
#define HDIM 64
#define EPS 1e-5f
#define MROWS (S_LEN*BATCH)  // 4096
#define QSCALE (0.03125f * 1.44269504088896f)

#define AS1 __attribute__((address_space(1)))
#define AS3 __attribute__((address_space(3)))

typedef __attribute__((ext_vector_type(8))) short bf8_t;
typedef __attribute__((ext_vector_type(4))) float f4_t;
typedef _Float16 __attribute__((ext_vector_type(8))) h8_t;
typedef _Float16 __attribute__((ext_vector_type(4))) h4_t;

#define MFMA16(a,b,c) __builtin_amdgcn_mfma_f32_16x16x16f16(a,b,c,0,0,0)

__device__ __forceinline__ float exp2_fast(float x){ return __builtin_exp2f(x); }

__device__ __forceinline__ unsigned short f2bf(float f){
  __hip_bfloat16 b = __float2bfloat16(f);
  return __builtin_bit_cast(unsigned short, b);
}
__device__ __forceinline__ float bf2f(unsigned short u){
  return __builtin_bit_cast(float, (unsigned)u << 16);
}
__device__ __forceinline__ float gelu_f(float x){
  return 0.5f * x * (1.0f + erff(x * 0.7071067811865475f));
}

// ------- prep: weight transposes (blocks 0..10751) + RMSNorm1 (rest) ---------
__global__ __launch_bounds__(256) void prep_k(const float* __restrict__ wq, const float* __restrict__ wk,
                                              const float* __restrict__ wv, const float* __restrict__ wo,
                                              const float* __restrict__ w1, const float* __restrict__ w2,
                                              __hip_bfloat16* __restrict__ wqkv_t, __hip_bfloat16* __restrict__ wo_t,
                                              __hip_bfloat16* __restrict__ w1_t,   __hip_bfloat16* __restrict__ w2_t,
                                              const float* __restrict__ x, const float* __restrict__ n1w,
                                              __hip_bfloat16* __restrict__ h){
  if (blockIdx.x < 10752){
    __shared__ float t[32][33];
    int b = blockIdx.x;
    const float* src; __hip_bfloat16* dst; int N, stride, nx;
    if (b < 1024)      { src=wq; dst=wqkv_t;               N=1024; stride=1024; nx=32;  }
    else if (b < 1280) { b-=1024; src=wk; dst=wqkv_t+1024*1024; N=256; stride=1024; nx=8; }
    else if (b < 1536) { b-=1280; src=wv; dst=wqkv_t+1280*1024; N=256; stride=1024; nx=8; }
    else if (b < 2560) { b-=1536; src=wo; dst=wo_t;        N=1024; stride=1024; nx=32;  }
    else if (b < 6656) { b-=2560; src=w1; dst=w1_t;        N=4096; stride=1024; nx=128; }
    else               { b-=6656; src=w2; dst=w2_t;        N=1024; stride=4096; nx=32;  }
    int n0 = (b % nx)*32, k0 = (b / nx)*32;
    int tx = threadIdx.x & 31, ty = threadIdx.x >> 5;
    #pragma unroll
    for (int i = 0; i < 4; ++i)
      t[ty*4+i][tx] = src[(size_t)(k0+ty*4+i)*N + n0 + tx];
    __syncthreads();
    #pragma unroll
    for (int i = 0; i < 4; ++i)
      dst[(size_t)(n0+ty*4+i)*stride + k0 + tx] = __float2bfloat16(t[tx][ty*4+i]);
  } else {
    __shared__ float sm[5];
    size_t row = blockIdx.x - 10752;
    const float4* xr = (const float4*)(x + row * DMODEL);
    float4 v = xr[threadIdx.x];
    float ss = v.x*v.x + v.y*v.y + v.z*v.z + v.w*v.w;
    #pragma unroll
    for (int off = 32; off; off >>= 1) ss += __shfl_down(ss, off);
    if ((threadIdx.x & 63) == 0) sm[threadIdx.x >> 6] = ss;
    __syncthreads();
    if (threadIdx.x == 0) sm[4] = rsqrtf((sm[0]+sm[1]+sm[2]+sm[3]) * (1.0f/DMODEL) + EPS);
    __syncthreads();
    float r = sm[4];
    float4 wv4 = ((const float4*)n1w)[threadIdx.x];
    ushort4 ob;
    ob.x = f2bf(v.x*r*wv4.x); ob.y = f2bf(v.y*r*wv4.y);
    ob.z = f2bf(v.z*r*wv4.z); ob.w = f2bf(v.w*r*wv4.w);
    ((ushort4*)(h + row * DMODEL))[threadIdx.x] = ob;
  }
}

// ---------------- bf16 MFMA GEMM v5: software-pipelined VGPR staging ---------
// C[M,N] = A[M,K] @ Wt[N,K]^T. 128x128 tile, BK=64, 4 waves (2x2), 4x4 16x16.
// Loads for tile t+1 issued BEFORE ds_write of tile t -> compiler emits
// vmcnt(8) (waits only t's loads, issued one compute-phase earlier).
// Chunked conflict-free LDS layout (verified 0 conflicts in R6/R7).
// EPI: 1 = +bias,gelu->bf16(Cb) ; 3 = raw bf16 partial -> Cb + z*MROWS*N
template<int EPI>
__global__ __launch_bounds__(256) void mgemm_k(const __hip_bfloat16* __restrict__ A,
                                               const __hip_bfloat16* __restrict__ Wt,
                                               const float* __restrict__ bias,
                                               __hip_bfloat16* __restrict__ Cb,
                                               int N, int Kstride, int kLen){
  __shared__ __align__(16) __hip_bfloat16 As[8192];   // 128 x 64
  __shared__ __align__(16) __hip_bfloat16 Bs[8192];
  const int tid = threadIdx.x;
  const int w = tid >> 6, l = tid & 63;
  const int lr = l & 15, lc = l >> 4;
  const int bm = blockIdx.y * 128, bn = blockIdx.x * 128;
  const int wm = (w >> 1) * 64, wn = (w & 1) * 64;
  const int kOff = blockIdx.z * kLen;

  const __hip_bfloat16* Ag = A  + (size_t)(bm + 2*w*16 + lr)*Kstride + kOff + lc*8;
  const __hip_bfloat16* Bg = Wt + (size_t)(bn + 2*w*16 + lr)*Kstride + kOff + lc*8;

  bf8_t ra0[4], rb0[4], ra1[4], rb1[4];
  f4_t acc[4][4] = {};

  #define GLOAD(RA, RB, K0) { \
    _Pragma("unroll") \
    for (int rg = 0; rg < 2; ++rg) \
      _Pragma("unroll") \
      for (int j = 0; j < 2; ++j){ \
        RA[rg*2+j] = *(const bf8_t*)(Ag + rg*16*(size_t)Kstride + (K0) + j*32); \
        RB[rg*2+j] = *(const bf8_t*)(Bg + rg*16*(size_t)Kstride + (K0) + j*32); \
      } }

  #define SWRITE(RA, RB) { \
    _Pragma("unroll") \
    for (int rg = 0; rg < 2; ++rg) \
      _Pragma("unroll") \
      for (int j = 0; j < 2; ++j){ \
        *(bf8_t*)(&As[(2*w+rg)*1024 + j*512 + l*8]) = RA[rg*2+j]; \
        *(bf8_t*)(&Bs[(2*w+rg)*1024 + j*512 + l*8]) = RB[rg*2+j]; \
      } }

  #define COMPUTE() { \
    _Pragma("unroll") \
    for (int s = 0; s < 2; ++s){ \
      bf8_t af[4], bfr[4]; \
      _Pragma("unroll") \
      for (int mi = 0; mi < 4; ++mi) \
        af[mi] = *(const bf8_t*)(&As[((wm>>4)+mi)*1024 + s*512 + l*8]); \
      _Pragma("unroll") \
      for (int ni = 0; ni < 4; ++ni) \
        bfr[ni] = *(const bf8_t*)(&Bs[((wn>>4)+ni)*1024 + s*512 + l*8]); \
      _Pragma("unroll") \
      for (int mi = 0; mi < 4; ++mi) \
        _Pragma("unroll") \
        for (int ni = 0; ni < 4; ++ni) \
          acc[mi][ni] = __builtin_amdgcn_mfma_f32_16x16x32_bf16(af[mi], bfr[ni], acc[mi][ni], 0, 0, 0); \
    } }

  const int n = kLen >> 6;        // 8 or 16 -> always even
  GLOAD(ra0, rb0, 0)
  for (int it = 0; it < n; it += 2){
    GLOAD(ra1, rb1, (it+1)*64)
    __syncthreads();              // prior readers of LDS done
    SWRITE(ra0, rb0)              // waits vmcnt(8): only ra0/rb0's loads
    __syncthreads();
    COMPUTE()
    if (it+2 < n) GLOAD(ra0, rb0, (it+2)*64)
    __syncthreads();
    SWRITE(ra1, rb1)
    __syncthreads();
    COMPUTE()
  }
  #undef GLOAD
  #undef SWRITE
  #undef COMPUTE

  __hip_bfloat16* Cp = (EPI == 3) ? (Cb + (size_t)blockIdx.z * ((size_t)MROWS * N)) : Cb;

  // C/D layout: col = lane&15 (=lr), row = (lane>>4)*4 + r (=lc*4+r)
  #pragma unroll
  for (int ni = 0; ni < 4; ++ni){
    int col = bn + wn + ni*16 + lr;
    float bb = (EPI == 3) ? 0.0f : bias[col];
    #pragma unroll
    for (int mi = 0; mi < 4; ++mi){
      #pragma unroll
      for (int r = 0; r < 4; ++r){
        int row = bm + wm + mi*16 + lc*4 + r;
        size_t off = (size_t)row * N + col;
        float v = acc[mi][ni][r] + bb;
        if (EPI == 1) Cp[off] = __float2bfloat16(gelu_f(v));
        else          Cp[off] = __float2bfloat16(v);
      }
    }
  }
}

// -------- split-K reduce: out = sum_bf16(partials) + bias + res (fp32) -------
template<int NS>
__global__ __launch_bounds__(256) void reduce_k(const unsigned short* __restrict__ P,
                                                const float* __restrict__ bias,
                                                const float* __restrict__ res,
                                                float* __restrict__ out, int N){
  size_t i = ((size_t)blockIdx.x*256 + threadIdx.x) * 4;
  int col = (int)(i % (size_t)N);
  size_t stride = (size_t)MROWS * N;
  float a0=0,a1=0,a2=0,a3=0;
  #pragma unroll
  for (int p = 0; p < NS; ++p){
    ushort4 u = *(const ushort4*)(P + p*stride + i);
    a0 += bf2f(u.x); a1 += bf2f(u.y); a2 += bf2f(u.z); a3 += bf2f(u.w);
  }
  float4 bb = *(const float4*)(bias + col);
  float4 r4 = *(const float4*)(res + i);
  float4 o = make_float4(a0+bb.x+r4.x, a1+bb.y+r4.y, a2+bb.z+r4.z, a3+bb.w+r4.w);
  *(float4*)(out + i) = o;
}

// ---- fused: wo split-2 reduce (+bias+res) -> x1, then RMSNorm2 -> h_bf ------
__global__ __launch_bounds__(256) void redn_k(const unsigned short* __restrict__ P,
                                              const float* __restrict__ bias,
                                              const float* __restrict__ res,
                                              const float* __restrict__ nw,
                                              float* __restrict__ x1,
                                              __hip_bfloat16* __restrict__ h){
  __shared__ float sm[5];
  size_t row = blockIdx.x;
  size_t i = row * DMODEL + threadIdx.x*4;
  size_t stride = (size_t)MROWS * DMODEL;
  ushort4 u0 = *(const ushort4*)(P + i);
  ushort4 u1 = *(const ushort4*)(P + stride + i);
  float4 bb = *(const float4*)(bias + threadIdx.x*4);
  float4 r4 = *(const float4*)(res + i);
  float4 v;
  v.x = bf2f(u0.x)+bf2f(u1.x)+bb.x+r4.x;
  v.y = bf2f(u0.y)+bf2f(u1.y)+bb.y+r4.y;
  v.z = bf2f(u0.z)+bf2f(u1.z)+bb.z+r4.z;
  v.w = bf2f(u0.w)+bf2f(u1.w)+bb.w+r4.w;
  *(float4*)(x1 + i) = v;
  float ss = v.x*v.x + v.y*v.y + v.z*v.z + v.w*v.w;
  #pragma unroll
  for (int off = 32; off; off >>= 1) ss += __shfl_down(ss, off);
  if ((threadIdx.x & 63) == 0) sm[threadIdx.x >> 6] = ss;
  __syncthreads();
  if (threadIdx.x == 0) sm[4] = rsqrtf((sm[0]+sm[1]+sm[2]+sm[3]) * (1.0f/DMODEL) + EPS);
  __syncthreads();
  float r = sm[4];
  float4 wv = ((const float4*)nw)[threadIdx.x];
  ushort4 ob;
  ob.x = f2bf(v.x*r*wv.x); ob.y = f2bf(v.y*r*wv.y);
  ob.z = f2bf(v.z*r*wv.z); ob.w = f2bf(v.w*r*wv.w);
  ((ushort4*)(h + row * DMODEL))[threadIdx.x] = ob;
}

// -------- per-head RMSNorm + RoPE -> f16, reads qkv partial pair + bias ------
__global__ __launch_bounds__(64) void rope2_k(const unsigned short* __restrict__ P,
                                              const float* __restrict__ bq, const float* __restrict__ bk,
                                              const float* __restrict__ qw, const float* __restrict__ kw,
                                              _Float16* __restrict__ qo, _Float16* __restrict__ ko){
  const int s = blockIdx.x;
  const int y = blockIdx.y;                  // b*20 + r ; r<16 -> Q head r, else K head r-16
  const int b = y / 20, r0 = y % 20;
  const bool isQ = (r0 < 16);
  const int hh = isQ ? r0 : (r0 - 16);
  const int col0 = isQ ? hh*64 : 1024 + hh*64;
  const int lane = threadIdx.x;
  const size_t pstride = (size_t)MROWS * 1536;
  size_t off = ((size_t)s * BATCH + b) * 1536 + col0 + lane;
  float v = bf2f(P[off]) + bf2f(P[off + pstride])
          + (isQ ? bq[hh*64 + lane] : bk[hh*64 + lane]);
  float ss = v * v;
  #pragma unroll
  for (int m = 32; m; m >>= 1) ss += __shfl_xor(ss, m);
  float rr = rsqrtf(ss * (1.0f/64.0f) + EPS);
  v = v * rr * (isQ ? qw[lane] : kw[lane]);
  int i = lane & 31;
  float invf = powf(10000.0f, -((float)(2*i)) * (1.0f/64.0f));
  float ang = (float)s * invf;
  float c, sn;
  sincosf(ang, &sn, &c);
  float partner = __shfl_xor(v, 32);
  float rh = (lane < 32) ? -partner : partner;
  float o = (v * c + rh * sn) * (isQ ? QSCALE : 1.0f);
  _Float16* outp = isQ ? (qo + (((size_t)b * NH  + hh) * S_LEN + s) * 64 + lane)
                       : (ko + (((size_t)b * NKV + hh) * S_LEN + s) * 64 + lane);
  *outp = (_Float16)o;
}

// -------- V extract from qkv partials -> Vt f16 [B*NKV][64][S] ---------------
__global__ __launch_bounds__(256) void vcast_k(const unsigned short* __restrict__ P,
                                               const float* __restrict__ bv,
                                               _Float16* __restrict__ Vt){
  __shared__ float t[64][65];
  const int s0 = blockIdx.x * 64;
  const int bkv = blockIdx.y;
  const int b = bkv >> 2, kv = bkv & 3;
  const int tid = threadIdx.x;
  const size_t pstride = (size_t)MROWS * 1536;
  #pragma unroll
  for (int i = 0; i < 16; ++i){
    int idx = tid + 256*i;
    int sl = idx >> 6, d = idx & 63;
    size_t off = ((size_t)(s0+sl)*BATCH + b)*1536 + 1280 + kv*64 + d;
    t[d][sl] = bf2f(P[off]) + bf2f(P[off + pstride]) + bv[kv*64 + d];
  }
  __syncthreads();
  #pragma unroll
  for (int i = 0; i < 16; ++i){
    int idx = tid + 256*i;
    int d = idx >> 6, sl = idx & 63;
    Vt[((size_t)bkv*64 + d)*S_LEN + s0 + sl] = (_Float16)t[d][sl];
  }
}

// ---------------- MFMA flash attention -------------------------------------
__global__ __launch_bounds__(256) void attn2_k(const _Float16* __restrict__ Q,
                                               const _Float16* __restrict__ K,
                                               const _Float16* __restrict__ Vt,
                                               __hip_bfloat16* __restrict__ AO){
  __shared__ __align__(16) _Float16 Ks[8*512];
  __shared__ __align__(16) _Float16 Vs[8*512];
  const int bh = blockIdx.x;
  const int qb = (gridDim.y - 1) - blockIdx.y;
  const int b = bh >> 4, h = bh & 15;
  const int kvh = h >> 2;
  const int tid = threadIdx.x;
  const int w = tid >> 6, l = tid & 63;
  const int lr = l & 15, quad = l >> 4;

  const _Float16* qp = Q + ((size_t)bh * S_LEN + qb*64 + w*16 + lr) * 64;
  h8_t qf0 = *(const h8_t*)(qp + quad*8);
  h8_t qf1 = *(const h8_t*)(qp + 32 + quad*8);

  const _Float16* kbase = K  + (size_t)(b*NKV + kvh) * S_LEN * 64;
  const _Float16* vbase = Vt + (size_t)(b*NKV + kvh) * 64 * S_LEN;

  f4_t Od[4] = {};
  float m_i = -3.0e38f, l_i = 0.0f;

  for (int kt = 0; kt <= qb; ++kt){
    __syncthreads();
    #pragma unroll
    for (int ii = 0; ii < 4; ++ii){
      int i = w*4 + ii;
      if (i < 8){
        int cc = i >> 1, dh = i & 1;
        const _Float16* src = kbase + (size_t)(kt*64 + cc*16 + lr)*64 + dh*32 + quad*8;
        __builtin_amdgcn_global_load_lds((const AS1 void*)src, (AS3 void*)(Ks + i*512), 16, 0, 0);
      } else {
        int j = i - 8;
        int dd = j >> 1, cc32 = j & 1;
        const _Float16* src = vbase + (size_t)(dd*16 + lr)*S_LEN + kt*64 + cc32*32 + quad*8;
        __builtin_amdgcn_global_load_lds((const AS1 void*)src, (AS3 void*)(Vs + j*512), 16, 0, 0);
      }
    }
    __syncthreads();

    const bool diag = (kt == qb);
    f4_t sc[4];
    #pragma unroll
    for (int nc2 = 0; nc2 < 4; ++nc2){
      if (diag && nc2 > w){
        sc[nc2][0] = -1.0e30f; sc[nc2][1] = -1.0e30f;
        sc[nc2][2] = -1.0e30f; sc[nc2][3] = -1.0e30f;
        continue;
      }
      f4_t a = {};
      h8_t k0 = *(const h8_t*)(Ks + (nc2*2+0)*512 + l*8);
      h8_t k1 = *(const h8_t*)(Ks + (nc2*2+1)*512 + l*8);
      a = __builtin_amdgcn_mfma_f32_16x16x32_f16(k0, qf0, a, 0, 0, 0);
      a = __builtin_amdgcn_mfma_f32_16x16x32_f16(k1, qf1, a, 0, 0, 0);
      if (diag && nc2 == w){
        #pragma unroll
        for (int r = 0; r < 4; ++r)
          if (quad*4 + r > lr) a[r] = -1.0e30f;
      }
      sc[nc2] = a;
    }

    float mx = sc[0][0];
    #pragma unroll
    for (int nc2 = 0; nc2 < 4; ++nc2)
      #pragma unroll
      for (int r = 0; r < 4; ++r) mx = fmaxf(mx, sc[nc2][r]);
    mx = fmaxf(mx, __shfl_xor(mx, 16));
    mx = fmaxf(mx, __shfl_xor(mx, 32));
    float nm = fmaxf(mx, m_i);
    float alpha = exp2_fast(m_i - nm);
    m_i = nm;
    float rs = 0.0f;
    h4_t pf[4];
    #pragma unroll
    for (int nc2 = 0; nc2 < 4; ++nc2)
      #pragma unroll
      for (int r = 0; r < 4; ++r){
        float e = exp2_fast(sc[nc2][r] - nm);
        rs += e;
        pf[nc2][r] = (_Float16)e;
      }
    rs += __shfl_xor(rs, 16);
    rs += __shfl_xor(rs, 32);
    l_i = l_i * alpha + rs;
    #pragma unroll
    for (int dd = 0; dd < 4; ++dd)
      #pragma unroll
      for (int r = 0; r < 4; ++r) Od[dd][r] *= alpha;

    #pragma unroll
    for (int dd = 0; dd < 4; ++dd)
      #pragma unroll
      for (int nc2 = 0; nc2 < 4; ++nc2){
        if (diag && nc2 > w) continue;
        h4_t vf = *(const h4_t*)(Vs + (dd*2 + (nc2>>1))*512
                                 + (((nc2&1)*2 + (quad>>1))*16 + lr)*8 + (quad&1)*4);
        Od[dd] = MFMA16(vf, pf[nc2], Od[dd]);
      }
  }

  float inv = 1.0f / l_i;
  #pragma unroll
  for (int dd = 0; dd < 4; ++dd){
    ushort4 w4;
    w4.x = f2bf(Od[dd][0]*inv); w4.y = f2bf(Od[dd][1]*inv);
    w4.z = f2bf(Od[dd][2]*inv); w4.w = f2bf(Od[dd][3]*inv);
    size_t sg = (size_t)qb*64 + w*16 + lr;
    *(ushort4*)(AO + (sg*BATCH + b)*DMODEL + h*64 + dd*16 + quad*4) = w4;
  }
}

extern "C" void kernel_launch(void* const* d_in, const int* in_sizes, int n_in,
                              void* d_out, int out_size, void* d_ws, size_t ws_size,
                              hipStream_t stream){
  const float* x   = (const float*)d_in[0];
  const float* n1w = (const float*)d_in[1];
  const float* wq  = (const float*)d_in[2];
  const float* bq  = (const float*)d_in[3];
  const float* wk  = (const float*)d_in[4];
  const float* bk  = (const float*)d_in[5];
  const float* wv  = (const float*)d_in[6];
  const float* bv  = (const float*)d_in[7];
  const float* qnw = (const float*)d_in[8];
  const float* knw = (const float*)d_in[9];
  const float* wo  = (const float*)d_in[10];
  const float* bo  = (const float*)d_in[11];
  const float* n2w = (const float*)d_in[12];
  const float* w1  = (const float*)d_in[13];
  const float* b1  = (const float*)d_in[14];
  const float* w2  = (const float*)d_in[15];
  const float* b2  = (const float*)d_in[16];
  float* out = (float*)d_out;

  char* p = (char*)d_ws;
  auto carve = [&](size_t bytes)->char*{ char* r = p; p += (bytes + 255) & ~(size_t)255; return r; };
  __hip_bfloat16* h_bf   = (__hip_bfloat16*)carve((size_t)MROWS*DMODEL*2);
  __hip_bfloat16* ao_bf  = (__hip_bfloat16*)carve((size_t)MROWS*DMODEL*2);
  __hip_bfloat16* mid_bf = (__hip_bfloat16*)carve((size_t)MROWS*4096*2);
  __hip_bfloat16* wqkv_t = (__hip_bfloat16*)carve((size_t)1536*1024*2);
  __hip_bfloat16* wo_t   = (__hip_bfloat16*)carve((size_t)1024*1024*2);
  __hip_bfloat16* w1_t   = (__hip_bfloat16*)carve((size_t)4096*1024*2);
  __hip_bfloat16* w2_t   = (__hip_bfloat16*)carve((size_t)1024*4096*2);
  __hip_bfloat16* qkv_p  = (__hip_bfloat16*)carve((size_t)2*MROWS*1536*2);  // qkv split-2 partials
  _Float16* q_f  = (_Float16*)carve((size_t)BATCH*NH *S_LEN*64*2);
  _Float16* k_f  = (_Float16*)carve((size_t)BATCH*NKV*S_LEN*64*2);
  _Float16* vt_f = (_Float16*)carve((size_t)BATCH*NKV*64*S_LEN*2);
  float* x1   = (float*)carve((size_t)MROWS*DMODEL*4);
  __hip_bfloat16* ps = (__hip_bfloat16*)carve((size_t)4*MROWS*DMODEL*2);    // wo(2)/w2(4) partials

  // weight prep + rmsnorm1 in one launch
  prep_k<<<10752 + MROWS, 256, 0, stream>>>(wq, wk, wv, wo, w1, w2,
                                            wqkv_t, wo_t, w1_t, w2_t, x, n1w, h_bf);

  // QKV: M=4096 N=1536 K=1024, split-K=2 (768 blocks), bf16 partials
  mgemm_k<3><<<dim3(12, 32, 2), 256, 0, stream>>>(h_bf, wqkv_t, nullptr, qkv_p, 1536, 1024, 512);

  rope2_k<<<dim3(S_LEN, BATCH*20), 64, 0, stream>>>((const unsigned short*)qkv_p, bq, bk, qnw, knw, q_f, k_f);
  vcast_k<<<dim3(S_LEN/64, BATCH*NKV), 256, 0, stream>>>((const unsigned short*)qkv_p, bv, vt_f);
  attn2_k<<<dim3(BATCH*NH, S_LEN/64), 256, 0, stream>>>(q_f, k_f, vt_f, ao_bf);

  // O-proj: M=4096 N=1024 K=1024, split-K=2 (512 blocks)
  mgemm_k<3><<<dim3(8, 32, 2), 256, 0, stream>>>(ao_bf, wo_t, nullptr, ps, 1024, 1024, 512);
  // fused: reduce(+bias+res) -> x1 AND rmsnorm2 -> h_bf
  redn_k<<<MROWS, 256, 0, stream>>>((const unsigned short*)ps, bo, x, n2w, x1, h_bf);

  // MLP up: M=4096 N=4096 K=1024 (1024 blocks), fused gelu->bf16
  mgemm_k<1><<<dim3(32, 32, 1), 256, 0, stream>>>(h_bf, w1_t, b1, mid_bf, 4096, 1024, 1024);

  // MLP down: M=4096 N=1024 K=4096, split-K=4 (1024 blocks)
  mgemm_k<3><<<dim3(8, 32, 4), 256, 0, stream>>>(mid_bf, w2_t, nullptr, ps, 1024, 4096, 1024);
  reduce_k<4><<<4096, 256, 0, stream>>>((const unsigned short*)ps, b2, x1, out, 1024);
}

// Round 9
// 430.446 us; speedup vs baseline: 1.1628x; 1.0159x over previous
//
#include <hip/hip_runtime.h>
#include <hip/hip_bf16.h>
#include <math.h>

#define S_LEN 2048
#define BATCH 2
#define DMODEL 1024
#define NH 16
#define NKV 4
#define HDIM 64
#define EPS 1e-5f
#define MROWS (S_LEN*BATCH)  // 4096
#define QSCALE (0.03125f * 1.44269504088896f)

#define AS1 __attribute__((address_space(1)))
#define AS3 __attribute__((address_space(3)))

typedef __attribute__((ext_vector_type(8))) short bf8_t;
typedef __attribute__((ext_vector_type(4))) float f4_t;
typedef _Float16 __attribute__((ext_vector_type(8))) h8_t;
typedef _Float16 __attribute__((ext_vector_type(4))) h4_t;

#define MFMA16(a,b,c) __builtin_amdgcn_mfma_f32_16x16x16f16(a,b,c,0,0,0)

__device__ __forceinline__ float exp2_fast(float x){ return __builtin_exp2f(x); }

__device__ __forceinline__ unsigned short f2bf(float f){
  __hip_bfloat16 b = __float2bfloat16(f);
  return __builtin_bit_cast(unsigned short, b);
}
__device__ __forceinline__ float bf2f(unsigned short u){
  return __builtin_bit_cast(float, (unsigned)u << 16);
}
__device__ __forceinline__ float gelu_f(float x){
  return 0.5f * x * (1.0f + erff(x * 0.7071067811865475f));
}

// ------- prep: weight transposes (blocks 0..10751) + RMSNorm1 (rest) ---------
__global__ __launch_bounds__(256) void prep_k(const float* __restrict__ wq, const float* __restrict__ wk,
                                              const float* __restrict__ wv, const float* __restrict__ wo,
                                              const float* __restrict__ w1, const float* __restrict__ w2,
                                              __hip_bfloat16* __restrict__ wqkv_t, __hip_bfloat16* __restrict__ wo_t,
                                              __hip_bfloat16* __restrict__ w1_t,   __hip_bfloat16* __restrict__ w2_t,
                                              const float* __restrict__ x, const float* __restrict__ n1w,
                                              __hip_bfloat16* __restrict__ h){
  if (blockIdx.x < 10752){
    __shared__ float t[32][33];
    int b = blockIdx.x;
    const float* src; __hip_bfloat16* dst; int N, stride, nx;
    if (b < 1024)      { src=wq; dst=wqkv_t;               N=1024; stride=1024; nx=32;  }
    else if (b < 1280) { b-=1024; src=wk; dst=wqkv_t+1024*1024; N=256; stride=1024; nx=8; }
    else if (b < 1536) { b-=1280; src=wv; dst=wqkv_t+1280*1024; N=256; stride=1024; nx=8; }
    else if (b < 2560) { b-=1536; src=wo; dst=wo_t;        N=1024; stride=1024; nx=32;  }
    else if (b < 6656) { b-=2560; src=w1; dst=w1_t;        N=4096; stride=1024; nx=128; }
    else               { b-=6656; src=w2; dst=w2_t;        N=1024; stride=4096; nx=32;  }
    int n0 = (b % nx)*32, k0 = (b / nx)*32;
    int tx = threadIdx.x & 31, ty = threadIdx.x >> 5;
    #pragma unroll
    for (int i = 0; i < 4; ++i)
      t[ty*4+i][tx] = src[(size_t)(k0+ty*4+i)*N + n0 + tx];
    __syncthreads();
    #pragma unroll
    for (int i = 0; i < 4; ++i)
      dst[(size_t)(n0+ty*4+i)*stride + k0 + tx] = __float2bfloat16(t[tx][ty*4+i]);
  } else {
    __shared__ float sm[5];
    size_t row = blockIdx.x - 10752;
    const float4* xr = (const float4*)(x + row * DMODEL);
    float4 v = xr[threadIdx.x];
    float ss = v.x*v.x + v.y*v.y + v.z*v.z + v.w*v.w;
    #pragma unroll
    for (int off = 32; off; off >>= 1) ss += __shfl_down(ss, off);
    if ((threadIdx.x & 63) == 0) sm[threadIdx.x >> 6] = ss;
    __syncthreads();
    if (threadIdx.x == 0) sm[4] = rsqrtf((sm[0]+sm[1]+sm[2]+sm[3]) * (1.0f/DMODEL) + EPS);
    __syncthreads();
    float r = sm[4];
    float4 wv4 = ((const float4*)n1w)[threadIdx.x];
    ushort4 ob;
    ob.x = f2bf(v.x*r*wv4.x); ob.y = f2bf(v.y*r*wv4.y);
    ob.z = f2bf(v.z*r*wv4.z); ob.w = f2bf(v.w*r*wv4.w);
    ((ushort4*)(h + row * DMODEL))[threadIdx.x] = ob;
  }
}

// ---------------- bf16 MFMA GEMM (R6/R7 proven version) ----------------------
// C[M,N] = A[M,K] @ Wt[N,K]^T. 128x128 tile, BK=64, 4 waves (2x2), 4x4 16x16.
// m97 2-barrier loop, global_load_lds staging, chunked conflict-free LDS
// layout [rowgroup(8)][kchunk(8)][row16(16)][8 bf16] (0 conflicts measured).
// EPI: 1 = +bias,gelu->bf16(Cb) ; 3 = raw bf16 partial -> Cb + z*MROWS*N
template<int EPI>
__global__ __launch_bounds__(256) void mgemm_k(const __hip_bfloat16* __restrict__ A,
                                               const __hip_bfloat16* __restrict__ Wt,
                                               const float* __restrict__ bias,
                                               __hip_bfloat16* __restrict__ Cb,
                                               int N, int Kstride, int kLen){
  __shared__ __align__(16) __hip_bfloat16 As[8192];   // 128 x 64
  __shared__ __align__(16) __hip_bfloat16 Bs[8192];
  const int tid = threadIdx.x;
  const int w = tid >> 6, l = tid & 63;
  const int lr = l & 15, lc = l >> 4;
  const int bm = blockIdx.y * 128, bn = blockIdx.x * 128;
  const int wm = (w >> 1) * 64, wn = (w & 1) * 64;
  const int kOff = blockIdx.z * kLen;

  const __hip_bfloat16* Ag = A  + (size_t)(bm + 2*w*16 + lr)*Kstride + kOff + lc*8;
  const __hip_bfloat16* Bg = Wt + (size_t)(bn + 2*w*16 + lr)*Kstride + kOff + lc*8;

  f4_t acc[4][4] = {};

  for (int k0 = 0; k0 < kLen; k0 += 64){
    __syncthreads();
    #pragma unroll
    for (int rg = 0; rg < 2; ++rg)
      #pragma unroll
      for (int j = 0; j < 2; ++j){
        __builtin_amdgcn_global_load_lds((const AS1 void*)(Ag + rg*16*(size_t)Kstride + k0 + j*32),
                                         (AS3 void*)(&As[(2*w+rg)*1024 + j*512 + l*8]), 16, 0, 0);
        __builtin_amdgcn_global_load_lds((const AS1 void*)(Bg + rg*16*(size_t)Kstride + k0 + j*32),
                                         (AS3 void*)(&Bs[(2*w+rg)*1024 + j*512 + l*8]), 16, 0, 0);
      }
    __syncthreads();
    #pragma unroll
    for (int s = 0; s < 2; ++s){
      bf8_t af[4], bfr[4];
      #pragma unroll
      for (int mi = 0; mi < 4; ++mi)
        af[mi] = *(const bf8_t*)(&As[((wm>>4)+mi)*1024 + s*512 + l*8]);
      #pragma unroll
      for (int ni = 0; ni < 4; ++ni)
        bfr[ni] = *(const bf8_t*)(&Bs[((wn>>4)+ni)*1024 + s*512 + l*8]);
      #pragma unroll
      for (int mi = 0; mi < 4; ++mi)
        #pragma unroll
        for (int ni = 0; ni < 4; ++ni)
          acc[mi][ni] = __builtin_amdgcn_mfma_f32_16x16x32_bf16(af[mi], bfr[ni], acc[mi][ni], 0, 0, 0);
    }
  }

  __hip_bfloat16* Cp = (EPI == 3) ? (Cb + (size_t)blockIdx.z * ((size_t)MROWS * N)) : Cb;

  // C/D layout: col = lane&15 (=lr), row = (lane>>4)*4 + r (=lc*4+r)
  #pragma unroll
  for (int ni = 0; ni < 4; ++ni){
    int col = bn + wn + ni*16 + lr;
    float bb = (EPI == 3) ? 0.0f : bias[col];
    #pragma unroll
    for (int mi = 0; mi < 4; ++mi){
      #pragma unroll
      for (int r = 0; r < 4; ++r){
        int row = bm + wm + mi*16 + lc*4 + r;
        size_t off = (size_t)row * N + col;
        float v = acc[mi][ni][r] + bb;
        if (EPI == 1) Cp[off] = __float2bfloat16(gelu_f(v));
        else          Cp[off] = __float2bfloat16(v);
      }
    }
  }
}

// -------- split-K reduce: out = sum_bf16(partials) + bias + res (fp32) -------
template<int NS>
__global__ __launch_bounds__(256) void reduce_k(const unsigned short* __restrict__ P,
                                                const float* __restrict__ bias,
                                                const float* __restrict__ res,
                                                float* __restrict__ out, int N){
  size_t i = ((size_t)blockIdx.x*256 + threadIdx.x) * 4;
  int col = (int)(i % (size_t)N);
  size_t stride = (size_t)MROWS * N;
  float a0=0,a1=0,a2=0,a3=0;
  #pragma unroll
  for (int p = 0; p < NS; ++p){
    ushort4 u = *(const ushort4*)(P + p*stride + i);
    a0 += bf2f(u.x); a1 += bf2f(u.y); a2 += bf2f(u.z); a3 += bf2f(u.w);
  }
  float4 bb = *(const float4*)(bias + col);
  float4 r4 = *(const float4*)(res + i);
  float4 o = make_float4(a0+bb.x+r4.x, a1+bb.y+r4.y, a2+bb.z+r4.z, a3+bb.w+r4.w);
  *(float4*)(out + i) = o;
}

// ---- fused: wo split-2 reduce (+bias+res) -> x1, then RMSNorm2 -> h_bf ------
__global__ __launch_bounds__(256) void redn_k(const unsigned short* __restrict__ P,
                                              const float* __restrict__ bias,
                                              const float* __restrict__ res,
                                              const float* __restrict__ nw,
                                              float* __restrict__ x1,
                                              __hip_bfloat16* __restrict__ h){
  __shared__ float sm[5];
  size_t row = blockIdx.x;
  size_t i = row * DMODEL + threadIdx.x*4;
  size_t stride = (size_t)MROWS * DMODEL;
  ushort4 u0 = *(const ushort4*)(P + i);
  ushort4 u1 = *(const ushort4*)(P + stride + i);
  float4 bb = *(const float4*)(bias + threadIdx.x*4);
  float4 r4 = *(const float4*)(res + i);
  float4 v;
  v.x = bf2f(u0.x)+bf2f(u1.x)+bb.x+r4.x;
  v.y = bf2f(u0.y)+bf2f(u1.y)+bb.y+r4.y;
  v.z = bf2f(u0.z)+bf2f(u1.z)+bb.z+r4.z;
  v.w = bf2f(u0.w)+bf2f(u1.w)+bb.w+r4.w;
  *(float4*)(x1 + i) = v;
  float ss = v.x*v.x + v.y*v.y + v.z*v.z + v.w*v.w;
  #pragma unroll
  for (int off = 32; off; off >>= 1) ss += __shfl_down(ss, off);
  if ((threadIdx.x & 63) == 0) sm[threadIdx.x >> 6] = ss;
  __syncthreads();
  if (threadIdx.x == 0) sm[4] = rsqrtf((sm[0]+sm[1]+sm[2]+sm[3]) * (1.0f/DMODEL) + EPS);
  __syncthreads();
  float r = sm[4];
  float4 wv = ((const float4*)nw)[threadIdx.x];
  ushort4 ob;
  ob.x = f2bf(v.x*r*wv.x); ob.y = f2bf(v.y*r*wv.y);
  ob.z = f2bf(v.z*r*wv.z); ob.w = f2bf(v.w*r*wv.w);
  ((ushort4*)(h + row * DMODEL))[threadIdx.x] = ob;
}

// -------- per-head RMSNorm + RoPE -> f16, reads qkv partial pair + bias ------
__global__ __launch_bounds__(64) void rope2_k(const unsigned short* __restrict__ P,
                                              const float* __restrict__ bq, const float* __restrict__ bk,
                                              const float* __restrict__ qw, const float* __restrict__ kw,
                                              _Float16* __restrict__ qo, _Float16* __restrict__ ko){
  const int s = blockIdx.x;
  const int y = blockIdx.y;                  // b*20 + r ; r<16 -> Q head r, else K head r-16
  const int b = y / 20, r0 = y % 20;
  const bool isQ = (r0 < 16);
  const int hh = isQ ? r0 : (r0 - 16);
  const int col0 = isQ ? hh*64 : 1024 + hh*64;
  const int lane = threadIdx.x;
  const size_t pstride = (size_t)MROWS * 1536;
  size_t off = ((size_t)s * BATCH + b) * 1536 + col0 + lane;
  float v = bf2f(P[off]) + bf2f(P[off + pstride])
          + (isQ ? bq[hh*64 + lane] : bk[hh*64 + lane]);
  float ss = v * v;
  #pragma unroll
  for (int m = 32; m; m >>= 1) ss += __shfl_xor(ss, m);
  float rr = rsqrtf(ss * (1.0f/64.0f) + EPS);
  v = v * rr * (isQ ? qw[lane] : kw[lane]);
  int i = lane & 31;
  float invf = powf(10000.0f, -((float)(2*i)) * (1.0f/64.0f));
  float ang = (float)s * invf;
  float c, sn;
  sincosf(ang, &sn, &c);
  float partner = __shfl_xor(v, 32);
  float rh = (lane < 32) ? -partner : partner;
  float o = (v * c + rh * sn) * (isQ ? QSCALE : 1.0f);
  _Float16* outp = isQ ? (qo + (((size_t)b * NH  + hh) * S_LEN + s) * 64 + lane)
                       : (ko + (((size_t)b * NKV + hh) * S_LEN + s) * 64 + lane);
  *outp = (_Float16)o;
}

// -------- V extract from qkv partials -> Vt f16 [B*NKV][64][S] ---------------
__global__ __launch_bounds__(256) void vcast_k(const unsigned short* __restrict__ P,
                                               const float* __restrict__ bv,
                                               _Float16* __restrict__ Vt){
  __shared__ float t[64][65];
  const int s0 = blockIdx.x * 64;
  const int bkv = blockIdx.y;
  const int b = bkv >> 2, kv = bkv & 3;
  const int tid = threadIdx.x;
  const size_t pstride = (size_t)MROWS * 1536;
  #pragma unroll
  for (int i = 0; i < 16; ++i){
    int idx = tid + 256*i;
    int sl = idx >> 6, d = idx & 63;
    size_t off = ((size_t)(s0+sl)*BATCH + b)*1536 + 1280 + kv*64 + d;
    t[d][sl] = bf2f(P[off]) + bf2f(P[off + pstride]) + bv[kv*64 + d];
  }
  __syncthreads();
  #pragma unroll
  for (int i = 0; i < 16; ++i){
    int idx = tid + 256*i;
    int d = idx >> 6, sl = idx & 63;
    Vt[((size_t)bkv*64 + d)*S_LEN + s0 + sl] = (_Float16)t[d][sl];
  }
}

// ---------------- MFMA flash attention -------------------------------------
__global__ __launch_bounds__(256) void attn2_k(const _Float16* __restrict__ Q,
                                               const _Float16* __restrict__ K,
                                               const _Float16* __restrict__ Vt,
                                               __hip_bfloat16* __restrict__ AO){
  __shared__ __align__(16) _Float16 Ks[8*512];
  __shared__ __align__(16) _Float16 Vs[8*512];
  const int bh = blockIdx.x;
  const int qb = (gridDim.y - 1) - blockIdx.y;
  const int b = bh >> 4, h = bh & 15;
  const int kvh = h >> 2;
  const int tid = threadIdx.x;
  const int w = tid >> 6, l = tid & 63;
  const int lr = l & 15, quad = l >> 4;

  const _Float16* qp = Q + ((size_t)bh * S_LEN + qb*64 + w*16 + lr) * 64;
  h8_t qf0 = *(const h8_t*)(qp + quad*8);
  h8_t qf1 = *(const h8_t*)(qp + 32 + quad*8);

  const _Float16* kbase = K  + (size_t)(b*NKV + kvh) * S_LEN * 64;
  const _Float16* vbase = Vt + (size_t)(b*NKV + kvh) * 64 * S_LEN;

  f4_t Od[4] = {};
  float m_i = -3.0e38f, l_i = 0.0f;

  for (int kt = 0; kt <= qb; ++kt){
    __syncthreads();
    #pragma unroll
    for (int ii = 0; ii < 4; ++ii){
      int i = w*4 + ii;
      if (i < 8){
        int cc = i >> 1, dh = i & 1;
        const _Float16* src = kbase + (size_t)(kt*64 + cc*16 + lr)*64 + dh*32 + quad*8;
        __builtin_amdgcn_global_load_lds((const AS1 void*)src, (AS3 void*)(Ks + i*512), 16, 0, 0);
      } else {
        int j = i - 8;
        int dd = j >> 1, cc32 = j & 1;
        const _Float16* src = vbase + (size_t)(dd*16 + lr)*S_LEN + kt*64 + cc32*32 + quad*8;
        __builtin_amdgcn_global_load_lds((const AS1 void*)src, (AS3 void*)(Vs + j*512), 16, 0, 0);
      }
    }
    __syncthreads();

    const bool diag = (kt == qb);
    f4_t sc[4];
    #pragma unroll
    for (int nc2 = 0; nc2 < 4; ++nc2){
      if (diag && nc2 > w){
        sc[nc2][0] = -1.0e30f; sc[nc2][1] = -1.0e30f;
        sc[nc2][2] = -1.0e30f; sc[nc2][3] = -1.0e30f;
        continue;
      }
      f4_t a = {};
      h8_t k0 = *(const h8_t*)(Ks + (nc2*2+0)*512 + l*8);
      h8_t k1 = *(const h8_t*)(Ks + (nc2*2+1)*512 + l*8);
      a = __builtin_amdgcn_mfma_f32_16x16x32_f16(k0, qf0, a, 0, 0, 0);
      a = __builtin_amdgcn_mfma_f32_16x16x32_f16(k1, qf1, a, 0, 0, 0);
      if (diag && nc2 == w){
        #pragma unroll
        for (int r = 0; r < 4; ++r)
          if (quad*4 + r > lr) a[r] = -1.0e30f;
      }
      sc[nc2] = a;
    }

    float mx = sc[0][0];
    #pragma unroll
    for (int nc2 = 0; nc2 < 4; ++nc2)
      #pragma unroll
      for (int r = 0; r < 4; ++r) mx = fmaxf(mx, sc[nc2][r]);
    mx = fmaxf(mx, __shfl_xor(mx, 16));
    mx = fmaxf(mx, __shfl_xor(mx, 32));
    float nm = fmaxf(mx, m_i);
    float alpha = exp2_fast(m_i - nm);
    m_i = nm;
    float rs = 0.0f;
    h4_t pf[4];
    #pragma unroll
    for (int nc2 = 0; nc2 < 4; ++nc2)
      #pragma unroll
      for (int r = 0; r < 4; ++r){
        float e = exp2_fast(sc[nc2][r] - nm);
        rs += e;
        pf[nc2][r] = (_Float16)e;
      }
    rs += __shfl_xor(rs, 16);
    rs += __shfl_xor(rs, 32);
    l_i = l_i * alpha + rs;
    #pragma unroll
    for (int dd = 0; dd < 4; ++dd)
      #pragma unroll
      for (int r = 0; r < 4; ++r) Od[dd][r] *= alpha;

    #pragma unroll
    for (int dd = 0; dd < 4; ++dd)
      #pragma unroll
      for (int nc2 = 0; nc2 < 4; ++nc2){
        if (diag && nc2 > w) continue;
        h4_t vf = *(const h4_t*)(Vs + (dd*2 + (nc2>>1))*512
                                 + (((nc2&1)*2 + (quad>>1))*16 + lr)*8 + (quad&1)*4);
        Od[dd] = MFMA16(vf, pf[nc2], Od[dd]);
      }
  }

  float inv = 1.0f / l_i;
  #pragma unroll
  for (int dd = 0; dd < 4; ++dd){
    ushort4 w4;
    w4.x = f2bf(Od[dd][0]*inv); w4.y = f2bf(Od[dd][1]*inv);
    w4.z = f2bf(Od[dd][2]*inv); w4.w = f2bf(Od[dd][3]*inv);
    size_t sg = (size_t)qb*64 + w*16 + lr;
    *(ushort4*)(AO + (sg*BATCH + b)*DMODEL + h*64 + dd*16 + quad*4) = w4;
  }
}

extern "C" void kernel_launch(void* const* d_in, const int* in_sizes, int n_in,
                              void* d_out, int out_size, void* d_ws, size_t ws_size,
                              hipStream_t stream){
  const float* x   = (const float*)d_in[0];
  const float* n1w = (const float*)d_in[1];
  const float* wq  = (const float*)d_in[2];
  const float* bq  = (const float*)d_in[3];
  const float* wk  = (const float*)d_in[4];
  const float* bk  = (const float*)d_in[5];
  const float* wv  = (const float*)d_in[6];
  const float* bv  = (const float*)d_in[7];
  const float* qnw = (const float*)d_in[8];
  const float* knw = (const float*)d_in[9];
  const float* wo  = (const float*)d_in[10];
  const float* bo  = (const float*)d_in[11];
  const float* n2w = (const float*)d_in[12];
  const float* w1  = (const float*)d_in[13];
  const float* b1  = (const float*)d_in[14];
  const float* w2  = (const float*)d_in[15];
  const float* b2  = (const float*)d_in[16];
  float* out = (float*)d_out;

  char* p = (char*)d_ws;
  auto carve = [&](size_t bytes)->char*{ char* r = p; p += (bytes + 255) & ~(size_t)255; return r; };
  __hip_bfloat16* h_bf   = (__hip_bfloat16*)carve((size_t)MROWS*DMODEL*2);
  __hip_bfloat16* ao_bf  = (__hip_bfloat16*)carve((size_t)MROWS*DMODEL*2);
  __hip_bfloat16* mid_bf = (__hip_bfloat16*)carve((size_t)MROWS*4096*2);
  __hip_bfloat16* wqkv_t = (__hip_bfloat16*)carve((size_t)1536*1024*2);
  __hip_bfloat16* wo_t   = (__hip_bfloat16*)carve((size_t)1024*1024*2);
  __hip_bfloat16* w1_t   = (__hip_bfloat16*)carve((size_t)4096*1024*2);
  __hip_bfloat16* w2_t   = (__hip_bfloat16*)carve((size_t)1024*4096*2);
  __hip_bfloat16* qkv_p  = (__hip_bfloat16*)carve((size_t)2*MROWS*1536*2);  // qkv split-2 partials
  _Float16* q_f  = (_Float16*)carve((size_t)BATCH*NH *S_LEN*64*2);
  _Float16* k_f  = (_Float16*)carve((size_t)BATCH*NKV*S_LEN*64*2);
  _Float16* vt_f = (_Float16*)carve((size_t)BATCH*NKV*64*S_LEN*2);
  float* x1   = (float*)carve((size_t)MROWS*DMODEL*4);
  __hip_bfloat16* ps = (__hip_bfloat16*)carve((size_t)2*MROWS*DMODEL*2);    // wo(2)/w2(2) partials

  // weight prep + rmsnorm1 in one launch
  prep_k<<<10752 + MROWS, 256, 0, stream>>>(wq, wk, wv, wo, w1, w2,
                                            wqkv_t, wo_t, w1_t, w2_t, x, n1w, h_bf);

  // QKV: M=4096 N=1536 K=1024, split-K=2 (768 blocks), bf16 partials
  mgemm_k<3><<<dim3(12, 32, 2), 256, 0, stream>>>(h_bf, wqkv_t, nullptr, qkv_p, 1536, 1024, 512);

  rope2_k<<<dim3(S_LEN, BATCH*20), 64, 0, stream>>>((const unsigned short*)qkv_p, bq, bk, qnw, knw, q_f, k_f);
  vcast_k<<<dim3(S_LEN/64, BATCH*NKV), 256, 0, stream>>>((const unsigned short*)qkv_p, bv, vt_f);
  attn2_k<<<dim3(BATCH*NH, S_LEN/64), 256, 0, stream>>>(q_f, k_f, vt_f, ao_bf);

  // O-proj: M=4096 N=1024 K=1024, split-K=2 (512 blocks)
  mgemm_k<3><<<dim3(8, 32, 2), 256, 0, stream>>>(ao_bf, wo_t, nullptr, ps, 1024, 1024, 512);
  // fused: reduce(+bias+res) -> x1 AND rmsnorm2 -> h_bf
  redn_k<<<MROWS, 256, 0, stream>>>((const unsigned short*)ps, bo, x, n2w, x1, h_bf);

  // MLP up: M=4096 N=4096 K=1024 (1024 blocks), fused gelu->bf16
  mgemm_k<1><<<dim3(32, 32, 1), 256, 0, stream>>>(h_bf, w1_t, b1, mid_bf, 4096, 1024, 1024);

  // MLP down: M=4096 N=1024 K=4096, split-K=2 (512 blocks)
  mgemm_k<3><<<dim3(8, 32, 2), 256, 0, stream>>>(mid_bf, w2_t, nullptr, ps, 1024, 4096, 2048);
  reduce_k<2><<<4096, 256, 0, stream>>>((const unsigned short*)ps, b2, x1, out, 1024);
}